// Round 15
// baseline (384.980 us; speedup 1.0000x reference)
//
#include <hip/hip_runtime.h>
#include <math.h>

#define N_NODES 100000
#define N_EDGES 1200000
#define N_GRAPHS 1000
#define HID 64
#define NBUCK 256
#define NPB   391
#define EDGE_CHUNK 16384
#define S3_BLOCKS ((N_EDGES + EDGE_CHUNK - 1) / EDGE_CHUNK)
#define LOG2E 1.4426950408889634f
#define N_TILES (N_NODES / 16)      // 6250, exact

typedef _Float16 half_t;
typedef __attribute__((ext_vector_type(4))) _Float16 half4;
typedef __attribute__((ext_vector_type(8))) _Float16 half8;
typedef __attribute__((ext_vector_type(4))) float floatx4;

// ---------------- CSR build via 2-level bucket sort --------------------------

__global__ void k_bhist(const int* __restrict__ ei, int* __restrict__ bucket_cnt) {
    __shared__ int hist[NBUCK];
    for (int t = threadIdx.x; t < NBUCK; t += blockDim.x) hist[t] = 0;
    __syncthreads();
    int e0 = blockIdx.x * EDGE_CHUNK;
    int e1 = min(e0 + EDGE_CHUNK, N_EDGES);
    for (int e = e0 + threadIdx.x; e < e1; e += blockDim.x)
        atomicAdd(&hist[ei[N_EDGES + e] / NPB], 1);
    __syncthreads();
    for (int t = threadIdx.x; t < NBUCK; t += blockDim.x)
        if (hist[t]) atomicAdd(&bucket_cnt[t], hist[t]);
}

__global__ void k_bscan(const int* __restrict__ bucket_cnt, int* __restrict__ bucket_base) {
    __shared__ int sh[NBUCK];
    int t = threadIdx.x;
    int v = bucket_cnt[t];
    sh[t] = v;
    __syncthreads();
    for (int off = 1; off < NBUCK; off <<= 1) {
        int u = (t >= off) ? sh[t - off] : 0;
        __syncthreads();
        sh[t] += u;
        __syncthreads();
    }
    bucket_base[t] = sh[t] - v;
    if (t == NBUCK - 1) bucket_base[NBUCK] = sh[t];
}

__global__ void k_bin(const int* __restrict__ ei, const int* __restrict__ bucket_base,
                      int* __restrict__ bucket_fill, int* __restrict__ staged) {
    __shared__ int hist[NBUCK];
    __shared__ int cursor[NBUCK];
    for (int t = threadIdx.x; t < NBUCK; t += blockDim.x) hist[t] = 0;
    __syncthreads();
    int e0 = blockIdx.x * EDGE_CHUNK;
    int e1 = min(e0 + EDGE_CHUNK, N_EDGES);
    for (int e = e0 + threadIdx.x; e < e1; e += blockDim.x)
        atomicAdd(&hist[ei[N_EDGES + e] / NPB], 1);
    __syncthreads();
    if (threadIdx.x < NBUCK) {
        int hv = hist[threadIdx.x];
        int start = bucket_base[threadIdx.x];
        if (hv) start += atomicAdd(&bucket_fill[threadIdx.x], hv);
        cursor[threadIdx.x] = start;
    }
    __syncthreads();
    for (int e = e0 + threadIdx.x; e < e1; e += blockDim.x) {
        int src = ei[e], dst = ei[N_EDGES + e];
        int b = dst / NPB;
        int ldst = dst - b * NPB;
        int pos = atomicAdd(&cursor[b], 1);
        staged[pos] = (ldst << 17) | src;
    }
}

__global__ void k_bcsr(const int* __restrict__ staged, const int* __restrict__ bucket_base,
                       int* __restrict__ rowptr, int* __restrict__ csr_src) {
    __shared__ int ldeg[NPB];
    __shared__ int sc[512];
    __shared__ int cursor[NPB];
    int b = blockIdx.x;
    int n0 = b * NPB;
    int n1 = min(n0 + NPB, N_NODES);
    int nn = n1 - n0;
    int bbase = bucket_base[b];
    int bcnt  = bucket_base[b+1] - bbase;
    for (int t = threadIdx.x; t < NPB; t += blockDim.x) ldeg[t] = 0;
    __syncthreads();
    for (int k = threadIdx.x; k < bcnt; k += blockDim.x)
        atomicAdd(&ldeg[staged[bbase + k] >> 17], 1);
    __syncthreads();
    if (threadIdx.x < 512) sc[threadIdx.x] = (threadIdx.x < nn) ? ldeg[threadIdx.x] : 0;
    __syncthreads();
    for (int off = 1; off < 512; off <<= 1) {
        int u = 0;
        if (threadIdx.x < 512 && threadIdx.x >= off) u = sc[threadIdx.x - off];
        __syncthreads();
        if (threadIdx.x < 512) sc[threadIdx.x] += u;
        __syncthreads();
    }
    if (threadIdx.x < nn) {
        int pre = sc[threadIdx.x] - ldeg[threadIdx.x];
        rowptr[n0 + threadIdx.x] = bbase + pre;
        cursor[threadIdx.x] = bbase + pre;
    }
    if (b == 0 && threadIdx.x == 0) rowptr[N_NODES] = bucket_base[NBUCK];
    __syncthreads();
    for (int k = threadIdx.x; k < bcnt; k += blockDim.x) {
        int v = staged[bbase + k];
        int pos = atomicAdd(&cursor[v >> 17], 1);
        csr_src[pos] = v & 0x1FFFF;
    }
}

// ---------------- fused climber LN + FiLM coefficient kernel -----------------
__global__ void k_climber_film(const float* __restrict__ climber,
                               const float* __restrict__ ln_g, const float* __restrict__ ln_b,
                               const float* __restrict__ W_c, const float* __restrict__ b_c,
                               const float* __restrict__ Wf1, const float* __restrict__ bf1,
                               const float* __restrict__ Wf2, const float* __restrict__ bf2,
                               float* __restrict__ gb1, float* __restrict__ gb2) {
    __shared__ float cl[64];
    int g = blockIdx.x;
    int j = threadIdx.x;
    if (j < 64) {
        float v[6];
        float mu = 0.f;
        #pragma unroll
        for (int k = 0; k < 6; k++) { v[k] = climber[g*6+k]; mu += v[k]; }
        mu *= (1.f/6.f);
        float var = 0.f;
        #pragma unroll
        for (int k = 0; k < 6; k++) { float d = v[k]-mu; var += d*d; }
        var *= (1.f/6.f);
        float rs = rsqrtf(var + 1e-5f);
        float acc = b_c[j];
        #pragma unroll
        for (int k = 0; k < 6; k++) {
            float cn = (v[k]-mu)*rs*ln_g[k] + ln_b[k];
            acc += cn * W_c[k*64+j];
        }
        cl[j] = fmaxf(acc, 0.f);
    }
    __syncthreads();
    float a1 = bf1[j], a2 = bf2[j];
    #pragma unroll 8
    for (int k = 0; k < 64; k++) {
        float ck = cl[k];
        a1 += ck * Wf1[k*128+j];
        a2 += ck * Wf2[k*128+j];
    }
    gb1[g*128+j] = a1;
    gb2[g*128+j] = a2;
}

// ---------------- shared device helpers --------------------------------------

__device__ __forceinline__ float4 h4_to_f4(half4 h) {
    float4 f;
    f.x = (float)h.x; f.y = (float)h.y; f.z = (float)h.z; f.w = (float)h.w;
    return f;
}

// cooperative, transposed W load: Wl[n][k] fp16 (so B frags are contiguous)
__device__ __forceinline__ void load_W_lds(const float* __restrict__ W, half_t* Wl) {
    for (int idx = threadIdx.x; idx < 4096; idx += 256) {
        int k = idx & 63, n = idx >> 6;
        Wl[n*64 + k] = (half_t)W[k*64 + n];
    }
}

// gather/softmax core for node i (16 lanes sl). z fp16, es/ed pre-scaled log2e.
__device__ __forceinline__ float4 gat_gather(int i, int sl,
    const int* __restrict__ rowptr, const int* __restrict__ csr_src,
    const float* __restrict__ es, const float* __restrict__ ed,
    const half_t* __restrict__ z, const float* __restrict__ bg) {
    int beg = rowptr[i], end = rowptr[i+1];
    int deg = end - beg;
    float edi = ed[i];

    float e_self = es[i] + edi;
    e_self = fmaxf(e_self, 0.2f * e_self);

    int svA = 0, svB = 0;
    float exA = 0.f, exB = 0.f;
    if (sl < deg) {
        svA = csr_src[beg + sl];
        float v = es[svA] + edi;
        exA = exp2f(fmaxf(v, 0.2f * v));
    }
    if (16 + sl < deg) {
        svB = csr_src[beg + 16 + sl];
        float v = es[svB] + edi;
        exB = exp2f(fmaxf(v, 0.2f * v));
    }
    float s = exA + exB;
    #pragma unroll
    for (int off = 1; off < 16; off <<= 1)
        s += __shfl_xor(s, off, 16);
    float ex = exp2f(e_self);
    s += ex;

    const half4* z4 = (const half4*)z;
    float4 zi = h4_to_f4(z4[i*16 + sl]);
    float4 acc = {ex*zi.x, ex*zi.y, ex*zi.z, ex*zi.w};

    int lim = (deg < 32) ? deg : 32;
    int k = 0;
    for (; k + 8 <= lim; k += 8) {
        int a[8]; float e[8];
        if (k < 16) {
            #pragma unroll
            for (int j = 0; j < 8; j++) {
                a[j] = __shfl(svA, k+j, 16);
                e[j] = __shfl(exA, k+j, 16);
            }
        } else {
            #pragma unroll
            for (int j = 0; j < 8; j++) {
                a[j] = __shfl(svB, k-16+j, 16);
                e[j] = __shfl(exB, k-16+j, 16);
            }
        }
        half4 q[8];
        #pragma unroll
        for (int j = 0; j < 8; j++) q[j] = z4[a[j]*16 + sl];
        #pragma unroll
        for (int j = 0; j < 8; j++) {
            float4 r = h4_to_f4(q[j]);
            acc.x += e[j]*r.x; acc.y += e[j]*r.y;
            acc.z += e[j]*r.z; acc.w += e[j]*r.w;
        }
    }
    for (; k + 4 <= lim; k += 4) {
        int a[4]; float e[4];
        if (k < 16) {
            #pragma unroll
            for (int j = 0; j < 4; j++) {
                a[j] = __shfl(svA, k+j, 16);
                e[j] = __shfl(exA, k+j, 16);
            }
        } else {
            #pragma unroll
            for (int j = 0; j < 4; j++) {
                a[j] = __shfl(svB, k-16+j, 16);
                e[j] = __shfl(exB, k-16+j, 16);
            }
        }
        half4 q[4];
        #pragma unroll
        for (int j = 0; j < 4; j++) q[j] = z4[a[j]*16 + sl];
        #pragma unroll
        for (int j = 0; j < 4; j++) {
            float4 r = h4_to_f4(q[j]);
            acc.x += e[j]*r.x; acc.y += e[j]*r.y;
            acc.z += e[j]*r.z; acc.w += e[j]*r.w;
        }
    }
    for (; k < lim; k++) {
        int a; float e2;
        if (k < 16) { a = __shfl(svA, k, 16);    e2 = __shfl(exA, k, 16); }
        else        { a = __shfl(svB, k-16, 16); e2 = __shfl(exB, k-16, 16); }
        float4 zr = h4_to_f4(z4[a*16 + sl]);
        acc.x += e2*zr.x; acc.y += e2*zr.y; acc.z += e2*zr.z; acc.w += e2*zr.w;
    }
    for (int kk = beg + 32; kk < end; kk++) {
        int sv = csr_src[kk];
        float v = es[sv] + edi;
        float e2 = exp2f(fmaxf(v, 0.2f * v));
        s += e2;
        float4 zr = h4_to_f4(z4[sv*16 + sl]);
        acc.x += e2*zr.x; acc.y += e2*zr.y; acc.z += e2*zr.z; acc.w += e2*zr.w;
    }
    float inv = 1.f / (s + 1e-16f);
    float4 bg4 = ((const float4*)bg)[sl];
    float4 o;
    o.x = fmaxf(acc.x*inv + bg4.x, 0.f);
    o.y = fmaxf(acc.y*inv + bg4.y, 0.f);
    o.z = fmaxf(acc.z*inv + bg4.z, 0.f);
    o.w = fmaxf(acc.w*inv + bg4.w, 0.f);
    return o;
}

// MFMA transform of the 16x64 LDS h-tile; wave `nt` computes N-cols 16nt..16nt+15.
// Emits z tile + es/ed (pre-scaled by LOG2E) via LDS staging.
// ht: stride-72 rows (padded); Wl: [n][k]; zl: 16x64; esp/edp: [4][16].
__device__ __forceinline__ void tile_mfma_z(int m0, int nt, int c, int g,
        const half_t* ht, const half_t* Wl, half_t* zl,
        float* esp, float* edp,
        const float* __restrict__ a_src, const float* __restrict__ a_dst) {
    half8 A0 = *(const half8*)&ht[c*72 + g*8];
    half8 A1 = *(const half8*)&ht[c*72 + 32 + g*8];
    half8 B0 = *(const half8*)&Wl[(c + 16*nt)*64 + g*8];
    half8 B1 = *(const half8*)&Wl[(c + 16*nt)*64 + 32 + g*8];
    floatx4 D = {0.f, 0.f, 0.f, 0.f};
    D = __builtin_amdgcn_mfma_f32_16x16x32_f16(A0, B0, D, 0, 0, 0);
    D = __builtin_amdgcn_mfma_f32_16x16x32_f16(A1, B1, D, 0, 0, 0);
    float as_v = a_src[16*nt + c] * LOG2E;
    float ad_v = a_dst[16*nt + c] * LOG2E;
    #pragma unroll
    for (int r = 0; r < 4; r++) {
        float ps = D[r] * as_v;
        float pd = D[r] * ad_v;
        #pragma unroll
        for (int off = 1; off < 16; off <<= 1) {
            ps += __shfl_xor(ps, off, 16);
            pd += __shfl_xor(pd, off, 16);
        }
        if (c == 0) {
            esp[nt*16 + g*4 + r] = ps;
            edp[nt*16 + g*4 + r] = pd;
        }
        zl[(g*4 + r)*64 + 16*nt + c] = (half_t)D[r];
    }
}

// ---------------- FUSED1: node-init + z1 = h@Wg1 + es1/ed1 -------------------
__global__ __launch_bounds__(256) void k_fused1(
        const float* __restrict__ x, const int* __restrict__ batch,
        const float* __restrict__ W_in, const float* __restrict__ b_in,
        const float* __restrict__ gb1, const float* __restrict__ Wg1,
        const float* __restrict__ as1, const float* __restrict__ ad1,
        half_t* __restrict__ z1, float* __restrict__ es1, float* __restrict__ ed1) {
    __shared__ half_t Wl[64*64];
    __shared__ half_t ht[16*72];
    __shared__ half_t zl[16*64];
    __shared__ float esp[64], edp[64];
    int m0 = blockIdx.x * 16;
    load_W_lds(Wg1, Wl);
    int il = threadIdx.x >> 4;
    int sl = threadIdx.x & 15;
    int i = m0 + il;
    float4 acc = ((const float4*)b_in)[sl];
    #pragma unroll
    for (int k = 0; k < 6; k++) {
        float xk = x[i*8+k];
        float4 w = ((const float4*)W_in)[k*16 + sl];
        acc.x += xk*w.x; acc.y += xk*w.y; acc.z += xk*w.z; acc.w += xk*w.w;
    }
    int g_ = batch[i];
    const float4* gb4 = (const float4*)gb1;
    float4 ga = gb4[g_*32 + sl];
    float4 be = gb4[g_*32 + 16 + sl];
    half4 hv;
    hv.x = (half_t)(acc.x*(1.f+ga.x) + be.x);
    hv.y = (half_t)(acc.y*(1.f+ga.y) + be.y);
    hv.z = (half_t)(acc.z*(1.f+ga.z) + be.z);
    hv.w = (half_t)(acc.w*(1.f+ga.w) + be.w);
    *(half4*)&ht[il*72 + sl*4] = hv;
    __syncthreads();
    int l = threadIdx.x & 63;
    tile_mfma_z(m0, threadIdx.x >> 6, l & 15, l >> 4, ht, Wl, zl, esp, edp, as1, ad1);
    __syncthreads();
    if (threadIdx.x < 128)
        ((half8*)(z1 + (size_t)m0*64))[threadIdx.x] = ((const half8*)zl)[threadIdx.x];
    else if (threadIdx.x < 144) {
        int r = threadIdx.x - 128;
        es1[m0 + r] = esp[r] + esp[16+r] + esp[32+r] + esp[48+r];
        ed1[m0 + r] = edp[r] + edp[16+r] + edp[32+r] + edp[48+r];
    }
}

// ---------------- FUSED2: agg1 + film2 + z2 = h@Wg2 + es2/ed2 ----------------
__global__ __launch_bounds__(256) void k_fused2(
        const int* __restrict__ rowptr, const int* __restrict__ csr_src,
        const float* __restrict__ es1, const float* __restrict__ ed1,
        const half_t* __restrict__ z1, const float* __restrict__ bg1,
        const int* __restrict__ batch, const float* __restrict__ gb2,
        const float* __restrict__ Wg2, const float* __restrict__ as2,
        const float* __restrict__ ad2,
        half_t* __restrict__ z2, float* __restrict__ es2, float* __restrict__ ed2) {
    __shared__ half_t Wl[64*64];
    __shared__ half_t ht[16*72];
    __shared__ half_t zl[16*64];
    __shared__ float esp[64], edp[64];
    int m0 = blockIdx.x * 16;
    load_W_lds(Wg2, Wl);
    int il = threadIdx.x >> 4;
    int sl = threadIdx.x & 15;
    int i = m0 + il;
    float4 o = gat_gather(i, sl, rowptr, csr_src, es1, ed1, z1, bg1);
    int g_ = batch[i];
    const float4* gb4 = (const float4*)gb2;
    float4 ga = gb4[g_*32 + sl];
    float4 be = gb4[g_*32 + 16 + sl];
    half4 hv;
    hv.x = (half_t)(o.x*(1.f+ga.x) + be.x);
    hv.y = (half_t)(o.y*(1.f+ga.y) + be.y);
    hv.z = (half_t)(o.z*(1.f+ga.z) + be.z);
    hv.w = (half_t)(o.w*(1.f+ga.w) + be.w);
    *(half4*)&ht[il*72 + sl*4] = hv;
    __syncthreads();
    int l = threadIdx.x & 63;
    tile_mfma_z(m0, threadIdx.x >> 6, l & 15, l >> 4, ht, Wl, zl, esp, edp, as2, ad2);
    __syncthreads();
    if (threadIdx.x < 128)
        ((half8*)(z2 + (size_t)m0*64))[threadIdx.x] = ((const half8*)zl)[threadIdx.x];
    else if (threadIdx.x < 144) {
        int r = threadIdx.x - 128;
        es2[m0 + r] = esp[r] + esp[16+r] + esp[32+r] + esp[48+r];
        ed2[m0 + r] = edp[r] + edp[16+r] + edp[32+r] + edp[48+r];
    }
}

// ---------------- FUSED3: agg2 + head --------------------------------------
__global__ __launch_bounds__(256) void k_fused3(
        const int* __restrict__ rowptr, const int* __restrict__ csr_src,
        const float* __restrict__ es2, const float* __restrict__ ed2,
        const half_t* __restrict__ z2, const float* __restrict__ bg2,
        const float* __restrict__ x,
        const float* __restrict__ Wc1, const float* __restrict__ bc1,
        const float* __restrict__ Wc2, const float* __restrict__ bc2,
        const float* __restrict__ Wh1, const float* __restrict__ bh1,
        const float* __restrict__ Wh2, const float* __restrict__ bh2,
        float* __restrict__ out) {
    __shared__ half_t Wl[64*64];
    __shared__ half_t ht[16*72];
    __shared__ float pp[4][16][4];
    int m0 = blockIdx.x * 16;
    load_W_lds(Wc1, Wl);
    int il = threadIdx.x >> 4;
    int sl = threadIdx.x & 15;
    int i = m0 + il;
    float4 o = gat_gather(i, sl, rowptr, csr_src, es2, ed2, z2, bg2);
    half4 hv;
    hv.x = (half_t)o.x; hv.y = (half_t)o.y; hv.z = (half_t)o.z; hv.w = (half_t)o.w;
    *(half4*)&ht[il*72 + sl*4] = hv;
    __syncthreads();
    int l = threadIdx.x & 63;
    int c = l & 15, g = l >> 4, nt = threadIdx.x >> 6;
    {
        half8 A0 = *(const half8*)&ht[c*72 + g*8];
        half8 A1 = *(const half8*)&ht[c*72 + 32 + g*8];
        half8 B0 = *(const half8*)&Wl[(c + 16*nt)*64 + g*8];
        half8 B1 = *(const half8*)&Wl[(c + 16*nt)*64 + 32 + g*8];
        floatx4 D = {0.f, 0.f, 0.f, 0.f};
        D = __builtin_amdgcn_mfma_f32_16x16x32_f16(A0, B0, D, 0, 0, 0);
        D = __builtin_amdgcn_mfma_f32_16x16x32_f16(A1, B1, D, 0, 0, 0);
        float bc1v = bc1[16*nt + c];
        float4 w2 = ((const float4*)Wc2)[16*nt + c];
        #pragma unroll
        for (int r = 0; r < 4; r++) {
            float tv = fmaxf(D[r] + bc1v, 0.f);
            float4 p;
            p.x = tv * w2.x; p.y = tv * w2.y; p.z = tv * w2.z; p.w = tv * w2.w;
            #pragma unroll
            for (int off = 1; off < 16; off <<= 1) {
                p.x += __shfl_xor(p.x, off, 16);
                p.y += __shfl_xor(p.y, off, 16);
                p.z += __shfl_xor(p.z, off, 16);
                p.w += __shfl_xor(p.w, off, 16);
            }
            if (c == 0) {
                pp[nt][g*4 + r][0] = p.x;
                pp[nt][g*4 + r][1] = p.y;
                pp[nt][g*4 + r][2] = p.z;
                pp[nt][g*4 + r][3] = p.w;
            }
        }
    }
    __syncthreads();
    if (threadIdx.x < 16) {
        int r = threadIdx.x;
        int m = m0 + r;
        float4 p;
        p.x = pp[0][r][0] + pp[1][r][0] + pp[2][r][0] + pp[3][r][0];
        p.y = pp[0][r][1] + pp[1][r][1] + pp[2][r][1] + pp[3][r][1];
        p.z = pp[0][r][2] + pp[1][r][2] + pp[2][r][2] + pp[3][r][2];
        p.w = pp[0][r][3] + pp[1][r][3] + pp[2][r][3] + pp[3][r][3];
        float f0 = x[m*8+6], f1 = x[m*8+7];
        float t8[8];
        #pragma unroll
        for (int q = 0; q < 8; q++)
            t8[q] = fmaxf(f0*Wh1[q] + f1*Wh1[8+q] + bh1[q], 0.f);
        float fl[4];
        #pragma unroll
        for (int q = 0; q < 4; q++) {
            float a = bh2[q];
            #pragma unroll
            for (int rr = 0; rr < 8; rr++) a += t8[rr]*Wh2[rr*4+q];
            fl[q] = a;
        }
        float4 ov;
        ov.x = p.x + bc2[0] + 0.03f*fl[0];
        ov.y = p.y + bc2[1] + 0.03f*fl[1];
        ov.z = p.z + bc2[2] + 0.03f*fl[2];
        ov.w = p.w + bc2[3] + 0.03f*fl[3];
        ((float4*)out)[m] = ov;
    }
}

extern "C" void kernel_launch(void* const* d_in, const int* in_sizes, int n_in,
                              void* d_out, int out_size, void* d_ws, size_t ws_size,
                              hipStream_t stream) {
    const float* x       = (const float*)d_in[0];
    const int*   ei      = (const int*)  d_in[1];
    const int*   batch   = (const int*)  d_in[2];
    const float* climber = (const float*)d_in[3];
    const float* W_in    = (const float*)d_in[4];
    const float* b_in    = (const float*)d_in[5];
    const float* ln_g    = (const float*)d_in[6];
    const float* ln_b    = (const float*)d_in[7];
    const float* W_c     = (const float*)d_in[8];
    const float* b_c     = (const float*)d_in[9];
    const float* Wf1     = (const float*)d_in[10];
    const float* bf1     = (const float*)d_in[11];
    const float* Wf2     = (const float*)d_in[12];
    const float* bf2     = (const float*)d_in[13];
    const float* Wg1     = (const float*)d_in[14];
    const float* as1     = (const float*)d_in[15];
    const float* ad1     = (const float*)d_in[16];
    const float* bg1     = (const float*)d_in[17];
    const float* Wg2     = (const float*)d_in[18];
    const float* as2     = (const float*)d_in[19];
    const float* ad2     = (const float*)d_in[20];
    const float* bg2     = (const float*)d_in[21];
    const float* Wc1     = (const float*)d_in[22];
    const float* bc1     = (const float*)d_in[23];
    const float* Wc2     = (const float*)d_in[24];
    const float* bc2     = (const float*)d_in[25];
    const float* Wh1     = (const float*)d_in[26];
    const float* bh1     = (const float*)d_in[27];
    const float* Wh2     = (const float*)d_in[28];
    const float* bh2     = (const float*)d_in[29];
    float* out = (float*)d_out;
    float* ws  = (float*)d_ws;

    // workspace carve (floats); no h buffer - tiles live in LDS
    float*  gb1         = ws;                       // 128,000
    float*  gb2         = gb1 + 128000;             // 128,000
    half_t* z1          = (half_t*)(gb2 + 128000);  // 6.4M halfs
    half_t* z2          = z1 + 6400000;             // 6.4M halfs
    float*  es1         = (float*)(z2 + 6400000);   // 100,000
    float*  ed1         = es1 + N_NODES;            // 100,000
    float*  es2         = ed1 + N_NODES;            // 100,000
    float*  ed2         = es2 + N_NODES;            // 100,000
    int*    rowptr      = (int*)(ed2 + N_NODES);    // 100,001
    int*    csr_src     = rowptr + N_NODES + 1;     // 1,200,000
    int*    bucket_cnt  = csr_src + N_EDGES;        // 256 (memset start)
    int*    bucket_fill = bucket_cnt + NBUCK;       // 256 (memset end)
    int*    bucket_base = bucket_fill + NBUCK;      // 257
    int*    staged      = bucket_base + NBUCK + 1;  // 1,200,000

    // CSR build via bucket sort
    hipMemsetAsync(bucket_cnt, 0, 2*NBUCK*sizeof(int), stream);
    k_bhist<<<S3_BLOCKS, 1024, 0, stream>>>(ei, bucket_cnt);
    k_bscan<<<1, NBUCK, 0, stream>>>(bucket_cnt, bucket_base);
    k_bin  <<<S3_BLOCKS, 1024, 0, stream>>>(ei, bucket_base, bucket_fill, staged);
    k_bcsr <<<NBUCK, 1024, 0, stream>>>(staged, bucket_base, rowptr, csr_src);

    // prologue
    k_climber_film<<<N_GRAPHS, 128, 0, stream>>>(climber, ln_g, ln_b, W_c, b_c,
                                                 Wf1, bf1, Wf2, bf2, gb1, gb2);

    k_fused1<<<N_TILES, 256, 0, stream>>>(x, batch, W_in, b_in, gb1, Wg1,
                                          as1, ad1, z1, es1, ed1);
    k_fused2<<<N_TILES, 256, 0, stream>>>(rowptr, csr_src, es1, ed1, z1, bg1,
                                          batch, gb2, Wg2, as2, ad2, z2, es2, ed2);
    k_fused3<<<N_TILES, 256, 0, stream>>>(rowptr, csr_src, es2, ed2, z2, bg2,
                                          x, Wc1, bc1, Wc2, bc2,
                                          Wh1, bh1, Wh2, bh2, out);
}

// Round 16
// 279.255 us; speedup vs baseline: 1.3786x; 1.3786x over previous
//
#include <hip/hip_runtime.h>
#include <math.h>

#define N_NODES 100000
#define N_EDGES 1200000
#define N_GRAPHS 1000
#define HID 64
#define NBUCK 256
#define NPB   391
#define EDGE_CHUNK 16384
#define S3_BLOCKS ((N_EDGES + EDGE_CHUNK - 1) / EDGE_CHUNK)
#define LOG2E 1.4426950408889634f
#define N_TILES (N_NODES / 16)      // 6250, exact
#define MFMA_BLOCKS 391

typedef _Float16 half_t;
typedef __attribute__((ext_vector_type(4))) _Float16 half4;
typedef __attribute__((ext_vector_type(8))) _Float16 half8;
typedef __attribute__((ext_vector_type(4))) float floatx4;

// ---------------- CSR build via 2-level bucket sort --------------------------
// staged entry: (local_dst << 17) | src   (src < 2^17, local_dst < 512)

__global__ void k_bhist(const int* __restrict__ ei, int* __restrict__ bucket_cnt) {
    __shared__ int hist[NBUCK];
    for (int t = threadIdx.x; t < NBUCK; t += blockDim.x) hist[t] = 0;
    __syncthreads();
    int e0 = blockIdx.x * EDGE_CHUNK;
    int e1 = min(e0 + EDGE_CHUNK, N_EDGES);
    for (int e = e0 + threadIdx.x; e < e1; e += blockDim.x)
        atomicAdd(&hist[ei[N_EDGES + e] / NPB], 1);
    __syncthreads();
    for (int t = threadIdx.x; t < NBUCK; t += blockDim.x)
        if (hist[t]) atomicAdd(&bucket_cnt[t], hist[t]);
}

__global__ void k_bscan(const int* __restrict__ bucket_cnt, int* __restrict__ bucket_base) {
    __shared__ int sh[NBUCK];
    int t = threadIdx.x;
    int v = bucket_cnt[t];
    sh[t] = v;
    __syncthreads();
    for (int off = 1; off < NBUCK; off <<= 1) {
        int u = (t >= off) ? sh[t - off] : 0;
        __syncthreads();
        sh[t] += u;
        __syncthreads();
    }
    bucket_base[t] = sh[t] - v;               // exclusive
    if (t == NBUCK - 1) bucket_base[NBUCK] = sh[t];
}

__global__ void k_bin(const int* __restrict__ ei, const int* __restrict__ bucket_base,
                      int* __restrict__ bucket_fill, int* __restrict__ staged) {
    __shared__ int hist[NBUCK];
    __shared__ int cursor[NBUCK];
    for (int t = threadIdx.x; t < NBUCK; t += blockDim.x) hist[t] = 0;
    __syncthreads();
    int e0 = blockIdx.x * EDGE_CHUNK;
    int e1 = min(e0 + EDGE_CHUNK, N_EDGES);
    for (int e = e0 + threadIdx.x; e < e1; e += blockDim.x)
        atomicAdd(&hist[ei[N_EDGES + e] / NPB], 1);
    __syncthreads();
    if (threadIdx.x < NBUCK) {
        int hv = hist[threadIdx.x];
        int start = bucket_base[threadIdx.x];
        if (hv) start += atomicAdd(&bucket_fill[threadIdx.x], hv);
        cursor[threadIdx.x] = start;
    }
    __syncthreads();
    for (int e = e0 + threadIdx.x; e < e1; e += blockDim.x) {
        int src = ei[e], dst = ei[N_EDGES + e];
        int b = dst / NPB;
        int ldst = dst - b * NPB;
        int pos = atomicAdd(&cursor[b], 1);
        staged[pos] = (ldst << 17) | src;
    }
}

__global__ void k_bcsr(const int* __restrict__ staged, const int* __restrict__ bucket_base,
                       int* __restrict__ rowptr, int* __restrict__ csr_src) {
    __shared__ int ldeg[NPB];
    __shared__ int sc[512];
    __shared__ int cursor[NPB];
    int b = blockIdx.x;
    int n0 = b * NPB;
    int n1 = min(n0 + NPB, N_NODES);
    int nn = n1 - n0;
    int bbase = bucket_base[b];
    int bcnt  = bucket_base[b+1] - bbase;
    for (int t = threadIdx.x; t < NPB; t += blockDim.x) ldeg[t] = 0;
    __syncthreads();
    for (int k = threadIdx.x; k < bcnt; k += blockDim.x)
        atomicAdd(&ldeg[staged[bbase + k] >> 17], 1);
    __syncthreads();
    if (threadIdx.x < 512) sc[threadIdx.x] = (threadIdx.x < nn) ? ldeg[threadIdx.x] : 0;
    __syncthreads();
    for (int off = 1; off < 512; off <<= 1) {
        int u = 0;
        if (threadIdx.x < 512 && threadIdx.x >= off) u = sc[threadIdx.x - off];
        __syncthreads();
        if (threadIdx.x < 512) sc[threadIdx.x] += u;
        __syncthreads();
    }
    if (threadIdx.x < nn) {
        int pre = sc[threadIdx.x] - ldeg[threadIdx.x];     // exclusive
        rowptr[n0 + threadIdx.x] = bbase + pre;
        cursor[threadIdx.x] = bbase + pre;
    }
    if (b == 0 && threadIdx.x == 0) rowptr[N_NODES] = bucket_base[NBUCK];
    __syncthreads();
    for (int k = threadIdx.x; k < bcnt; k += blockDim.x) {
        int v = staged[bbase + k];
        int pos = atomicAdd(&cursor[v >> 17], 1);
        csr_src[pos] = v & 0x1FFFF;
    }
}

// ---------------- fused climber LN + FiLM coefficient kernel -----------------
__global__ void k_climber_film(const float* __restrict__ climber,
                               const float* __restrict__ ln_g, const float* __restrict__ ln_b,
                               const float* __restrict__ W_c, const float* __restrict__ b_c,
                               const float* __restrict__ Wf1, const float* __restrict__ bf1,
                               const float* __restrict__ Wf2, const float* __restrict__ bf2,
                               float* __restrict__ gb1, float* __restrict__ gb2) {
    __shared__ float cl[64];
    int g = blockIdx.x;
    int j = threadIdx.x;
    if (j < 64) {
        float v[6];
        float mu = 0.f;
        #pragma unroll
        for (int k = 0; k < 6; k++) { v[k] = climber[g*6+k]; mu += v[k]; }
        mu *= (1.f/6.f);
        float var = 0.f;
        #pragma unroll
        for (int k = 0; k < 6; k++) { float d = v[k]-mu; var += d*d; }
        var *= (1.f/6.f);
        float rs = rsqrtf(var + 1e-5f);
        float acc = b_c[j];
        #pragma unroll
        for (int k = 0; k < 6; k++) {
            float cn = (v[k]-mu)*rs*ln_g[k] + ln_b[k];
            acc += cn * W_c[k*64+j];
        }
        cl[j] = fmaxf(acc, 0.f);
    }
    __syncthreads();
    float a1 = bf1[j], a2 = bf2[j];
    #pragma unroll 8
    for (int k = 0; k < 64; k++) {
        float ck = cl[k];
        a1 += ck * Wf1[k*128+j];
        a2 += ck * Wf2[k*128+j];
    }
    gb1[g*128+j] = a1;
    gb2[g*128+j] = a2;
}

// ---------------- node init: h1 = film1(x@W_in + b_in), fp16 ----------------
__global__ void k_node0(const float* __restrict__ x, const int* __restrict__ batch,
                        const float* __restrict__ W_in, const float* __restrict__ b_in,
                        const float* __restrict__ gb1, half_t* __restrict__ h) {
    int tid = blockIdx.x * blockDim.x + threadIdx.x;
    int i  = tid >> 4;
    int sl = threadIdx.x & 15;
    if (i >= N_NODES) return;
    float4 acc = ((const float4*)b_in)[sl];
    #pragma unroll
    for (int k = 0; k < 6; k++) {
        float xk = x[i*8+k];
        float4 w = ((const float4*)W_in)[k*16 + sl];
        acc.x += xk*w.x; acc.y += xk*w.y; acc.z += xk*w.z; acc.w += xk*w.w;
    }
    int g = batch[i];
    const float4* gb4 = (const float4*)gb1;
    float4 ga = gb4[g*32 + sl];
    float4 be = gb4[g*32 + 16 + sl];
    half4 hv;
    hv.x = (half_t)(acc.x*(1.f+ga.x) + be.x);
    hv.y = (half_t)(acc.y*(1.f+ga.y) + be.y);
    hv.z = (half_t)(acc.z*(1.f+ga.z) + be.z);
    hv.w = (half_t)(acc.w*(1.f+ga.w) + be.w);
    ((half4*)h)[i*16 + sl] = hv;
}

// ---------------- MFMA transform: z = h @ W (fp16 in, fp32 acc) -------------
// 16-node tiles. A: row=lane&15, k=(lane>>4)*8+j.  B: col=lane&15, same k.
// D (verified layout): col=lane&15, row=(lane>>4)*4+reg.
// Also emits es = z@a_src * LOG2E, ed = z@a_dst * LOG2E from fp32 D frags.
__global__ __launch_bounds__(256) void k_mfma_z(
        const half_t* __restrict__ h, const float* __restrict__ W,
        const float* __restrict__ a_src, const float* __restrict__ a_dst,
        half_t* __restrict__ z, float* __restrict__ es, float* __restrict__ ed) {
    __shared__ half_t zl[4][16*64];          // per-wave 2 KB transpose staging
    int wave = threadIdx.x >> 6;
    int l    = threadIdx.x & 63;
    int c    = l & 15;
    int g    = l >> 4;
    // B fragments (held in VGPRs for all tiles): B[k][n], k=ko*32+g*8+j, n=c+16*nt
    half8 Bf[2][4];
    #pragma unroll
    for (int ko = 0; ko < 2; ko++) {
        #pragma unroll
        for (int nt = 0; nt < 4; nt++) {
            half8 b;
            #pragma unroll
            for (int j = 0; j < 8; j++)
                b[j] = (half_t)W[(ko*32 + g*8 + j)*64 + c + 16*nt];
            Bf[ko][nt] = b;
        }
    }
    float as4[4], ad4[4];
    #pragma unroll
    for (int nt = 0; nt < 4; nt++) {
        as4[nt] = a_src[c + 16*nt] * LOG2E;
        ad4[nt] = a_dst[c + 16*nt] * LOG2E;
    }
    int nWaves = gridDim.x * 4;
    int wid = blockIdx.x * 4 + wave;
    half_t* zw = zl[wave];
    for (int t = wid; t < N_TILES; t += nWaves) {
        int m0 = t * 16;
        const half8* hrow = (const half8*)(h + (size_t)(m0 + c) * 64);
        half8 A0 = hrow[g];          // k 0..31 slice for this lane
        half8 A1 = hrow[g + 4];      // k 32..63
        floatx4 D[4];
        #pragma unroll
        for (int nt = 0; nt < 4; nt++) {
            floatx4 acc = {0.f, 0.f, 0.f, 0.f};
            acc = __builtin_amdgcn_mfma_f32_16x16x32_f16(A0, Bf[0][nt], acc, 0, 0, 0);
            acc = __builtin_amdgcn_mfma_f32_16x16x32_f16(A1, Bf[1][nt], acc, 0, 0, 0);
            D[nt] = acc;
        }
        // es/ed: row m0+g*4+r spread over lanes c=0..15
        #pragma unroll
        for (int r = 0; r < 4; r++) {
            float ps = D[0][r]*as4[0] + D[1][r]*as4[1] + D[2][r]*as4[2] + D[3][r]*as4[3];
            float pd = D[0][r]*ad4[0] + D[1][r]*ad4[1] + D[2][r]*ad4[2] + D[3][r]*ad4[3];
            #pragma unroll
            for (int off = 1; off < 16; off <<= 1) {
                ps += __shfl_xor(ps, off, 16);
                pd += __shfl_xor(pd, off, 16);
            }
            if (c == 0) {
                es[m0 + g*4 + r] = ps;
                ed[m0 + g*4 + r] = pd;
            }
        }
        // transpose D -> row-major z via wave-private LDS, then coalesced store
        #pragma unroll
        for (int nt = 0; nt < 4; nt++) {
            #pragma unroll
            for (int r = 0; r < 4; r++)
                zw[(g*4 + r)*64 + c + 16*nt] = (half_t)D[nt][r];
        }
        __asm__ __volatile__("s_waitcnt lgkmcnt(0)" ::: "memory");
        const half8* zr = (const half8*)zw;
        half8 v0 = zr[l*2];
        half8 v1 = zr[l*2 + 1];
        half8* zo = (half8*)(z + (size_t)m0 * 64);
        zo[l*2]     = v0;
        zo[l*2 + 1] = v1;
        __asm__ __volatile__("s_waitcnt lgkmcnt(0)" ::: "memory");
    }
}

// ---------------- gather/softmax aggregation (no transform) ------------------
// 4 nodes/wave, 16 lanes/node. z fp16; es/ed pre-scaled by log2(e); no max
// (scores bounded, exp2 safe in fp32; alpha = e_k/sum identical).
__device__ __forceinline__ float4 h4_to_f4(half4 h) {
    float4 f;
    f.x = (float)h.x; f.y = (float)h.y; f.z = (float)h.z; f.w = (float)h.w;
    return f;
}

__global__ void k_agg(const int* __restrict__ rowptr, const int* __restrict__ csr_src,
                      const float* __restrict__ es, const float* __restrict__ ed,
                      const half_t* __restrict__ z, const float* __restrict__ bg,
                      const int* __restrict__ batch, const float* __restrict__ gb,
                      int apply_film, half_t* __restrict__ hout) {
    int tid = blockIdx.x * blockDim.x + threadIdx.x;
    int i  = tid >> 4;
    int sl = threadIdx.x & 15;
    if (i >= N_NODES) return;
    int beg = rowptr[i], end = rowptr[i+1];
    int deg = end - beg;
    float edi = ed[i];

    float e_self = es[i] + edi;
    e_self = fmaxf(e_self, 0.2f * e_self);

    int svA = 0, svB = 0;
    float exA = 0.f, exB = 0.f;
    if (sl < deg) {
        svA = csr_src[beg + sl];
        float v = es[svA] + edi;
        exA = exp2f(fmaxf(v, 0.2f * v));
    }
    if (16 + sl < deg) {
        svB = csr_src[beg + 16 + sl];
        float v = es[svB] + edi;
        exB = exp2f(fmaxf(v, 0.2f * v));
    }
    float s = exA + exB;
    #pragma unroll
    for (int off = 1; off < 16; off <<= 1)
        s += __shfl_xor(s, off, 16);
    float ex = exp2f(e_self);
    s += ex;

    const half4* z4 = (const half4*)z;
    float4 zi = h4_to_f4(z4[i*16 + sl]);
    float4 acc = {ex*zi.x, ex*zi.y, ex*zi.z, ex*zi.w};

    int lim = (deg < 32) ? deg : 32;
    int k = 0;
    for (; k + 8 <= lim; k += 8) {
        int a[8]; float e[8];
        if (k < 16) {
            #pragma unroll
            for (int j = 0; j < 8; j++) {
                a[j] = __shfl(svA, k+j, 16);
                e[j] = __shfl(exA, k+j, 16);
            }
        } else {
            #pragma unroll
            for (int j = 0; j < 8; j++) {
                a[j] = __shfl(svB, k-16+j, 16);
                e[j] = __shfl(exB, k-16+j, 16);
            }
        }
        half4 q[8];
        #pragma unroll
        for (int j = 0; j < 8; j++) q[j] = z4[a[j]*16 + sl];
        #pragma unroll
        for (int j = 0; j < 8; j++) {
            float4 r = h4_to_f4(q[j]);
            acc.x += e[j]*r.x; acc.y += e[j]*r.y;
            acc.z += e[j]*r.z; acc.w += e[j]*r.w;
        }
    }
    for (; k + 4 <= lim; k += 4) {
        int a[4]; float e[4];
        if (k < 16) {
            #pragma unroll
            for (int j = 0; j < 4; j++) {
                a[j] = __shfl(svA, k+j, 16);
                e[j] = __shfl(exA, k+j, 16);
            }
        } else {
            #pragma unroll
            for (int j = 0; j < 4; j++) {
                a[j] = __shfl(svB, k-16+j, 16);
                e[j] = __shfl(exB, k-16+j, 16);
            }
        }
        half4 q[4];
        #pragma unroll
        for (int j = 0; j < 4; j++) q[j] = z4[a[j]*16 + sl];
        #pragma unroll
        for (int j = 0; j < 4; j++) {
            float4 r = h4_to_f4(q[j]);
            acc.x += e[j]*r.x; acc.y += e[j]*r.y;
            acc.z += e[j]*r.z; acc.w += e[j]*r.w;
        }
    }
    for (; k < lim; k++) {
        int a; float e2;
        if (k < 16) { a = __shfl(svA, k, 16);    e2 = __shfl(exA, k, 16); }
        else        { a = __shfl(svB, k-16, 16); e2 = __shfl(exB, k-16, 16); }
        float4 zr = h4_to_f4(z4[a*16 + sl]);
        acc.x += e2*zr.x; acc.y += e2*zr.y; acc.z += e2*zr.z; acc.w += e2*zr.w;
    }
    for (int kk = beg + 32; kk < end; kk++) {   // rare: deg > 32
        int sv = csr_src[kk];
        float v = es[sv] + edi;
        float e2 = exp2f(fmaxf(v, 0.2f * v));
        s += e2;
        float4 zr = h4_to_f4(z4[sv*16 + sl]);
        acc.x += e2*zr.x; acc.y += e2*zr.y; acc.z += e2*zr.z; acc.w += e2*zr.w;
    }
    float inv = 1.f / (s + 1e-16f);
    float4 bg4 = ((const float4*)bg)[sl];
    float4 o;
    o.x = fmaxf(acc.x*inv + bg4.x, 0.f);
    o.y = fmaxf(acc.y*inv + bg4.y, 0.f);
    o.z = fmaxf(acc.z*inv + bg4.z, 0.f);
    o.w = fmaxf(acc.w*inv + bg4.w, 0.f);
    if (apply_film) {
        int g = batch[i];
        const float4* gb4 = (const float4*)gb;
        float4 ga = gb4[g*32 + sl];
        float4 be = gb4[g*32 + 16 + sl];
        o.x = o.x*(1.f+ga.x) + be.x;
        o.y = o.y*(1.f+ga.y) + be.y;
        o.z = o.z*(1.f+ga.z) + be.z;
        o.w = o.w*(1.f+ga.w) + be.w;
    }
    half4 hv;
    hv.x = (half_t)o.x; hv.y = (half_t)o.y; hv.z = (half_t)o.z; hv.w = (half_t)o.w;
    ((half4*)hout)[i*16 + sl] = hv;
}

// ---------------- MFMA head: out = relu(h@Wc1+bc1)@Wc2+bc2 + 0.03*flags -----
__global__ __launch_bounds__(256) void k_head_mfma(
        const half_t* __restrict__ h, const float* __restrict__ x,
        const float* __restrict__ Wc1, const float* __restrict__ bc1,
        const float* __restrict__ Wc2, const float* __restrict__ bc2,
        const float* __restrict__ Wh1, const float* __restrict__ bh1,
        const float* __restrict__ Wh2, const float* __restrict__ bh2,
        float* __restrict__ out) {
    int l    = threadIdx.x & 63;
    int c    = l & 15;
    int g    = l >> 4;
    half8 Bf[2][4];
    #pragma unroll
    for (int ko = 0; ko < 2; ko++) {
        #pragma unroll
        for (int nt = 0; nt < 4; nt++) {
            half8 b;
            #pragma unroll
            for (int j = 0; j < 8; j++)
                b[j] = (half_t)Wc1[(ko*32 + g*8 + j)*64 + c + 16*nt];
            Bf[ko][nt] = b;
        }
    }
    float bc1v[4];
    float4 w2[4];
    #pragma unroll
    for (int nt = 0; nt < 4; nt++) {
        bc1v[nt] = bc1[c + 16*nt];
        w2[nt] = ((const float4*)Wc2)[c + 16*nt];   // Wc2 row (c+16nt), 4 outputs
    }
    int nWaves = gridDim.x * 4;
    int wid = blockIdx.x * 4 + (threadIdx.x >> 6);
    for (int t = wid; t < N_TILES; t += nWaves) {
        int m0 = t * 16;
        const half8* hrow = (const half8*)(h + (size_t)(m0 + c) * 64);
        half8 A0 = hrow[g];
        half8 A1 = hrow[g + 4];
        floatx4 D[4];
        #pragma unroll
        for (int nt = 0; nt < 4; nt++) {
            floatx4 acc = {0.f, 0.f, 0.f, 0.f};
            acc = __builtin_amdgcn_mfma_f32_16x16x32_f16(A0, Bf[0][nt], acc, 0, 0, 0);
            acc = __builtin_amdgcn_mfma_f32_16x16x32_f16(A1, Bf[1][nt], acc, 0, 0, 0);
            D[nt] = acc;
        }
        #pragma unroll
        for (int r = 0; r < 4; r++) {
            float4 p = {0.f, 0.f, 0.f, 0.f};
            #pragma unroll
            for (int nt = 0; nt < 4; nt++) {
                float tv = fmaxf(D[nt][r] + bc1v[nt], 0.f);
                p.x += tv * w2[nt].x;
                p.y += tv * w2[nt].y;
                p.z += tv * w2[nt].z;
                p.w += tv * w2[nt].w;
            }
            #pragma unroll
            for (int off = 1; off < 16; off <<= 1) {
                p.x += __shfl_xor(p.x, off, 16);
                p.y += __shfl_xor(p.y, off, 16);
                p.z += __shfl_xor(p.z, off, 16);
                p.w += __shfl_xor(p.w, off, 16);
            }
            if (c == 0) {
                int m = m0 + g*4 + r;
                float f0 = x[m*8+6], f1 = x[m*8+7];
                float t8[8];
                #pragma unroll
                for (int q = 0; q < 8; q++)
                    t8[q] = fmaxf(f0*Wh1[q] + f1*Wh1[8+q] + bh1[q], 0.f);
                float fl[4];
                #pragma unroll
                for (int q = 0; q < 4; q++) {
                    float a = bh2[q];
                    #pragma unroll
                    for (int rr = 0; rr < 8; rr++) a += t8[rr]*Wh2[rr*4+q];
                    fl[q] = a;
                }
                float4 ov;
                ov.x = p.x + bc2[0] + 0.03f*fl[0];
                ov.y = p.y + bc2[1] + 0.03f*fl[1];
                ov.z = p.z + bc2[2] + 0.03f*fl[2];
                ov.w = p.w + bc2[3] + 0.03f*fl[3];
                ((float4*)out)[m] = ov;
            }
        }
    }
}

extern "C" void kernel_launch(void* const* d_in, const int* in_sizes, int n_in,
                              void* d_out, int out_size, void* d_ws, size_t ws_size,
                              hipStream_t stream) {
    const float* x       = (const float*)d_in[0];
    const int*   ei      = (const int*)  d_in[1];
    const int*   batch   = (const int*)  d_in[2];
    const float* climber = (const float*)d_in[3];
    const float* W_in    = (const float*)d_in[4];
    const float* b_in    = (const float*)d_in[5];
    const float* ln_g    = (const float*)d_in[6];
    const float* ln_b    = (const float*)d_in[7];
    const float* W_c     = (const float*)d_in[8];
    const float* b_c     = (const float*)d_in[9];
    const float* Wf1     = (const float*)d_in[10];
    const float* bf1     = (const float*)d_in[11];
    const float* Wf2     = (const float*)d_in[12];
    const float* bf2     = (const float*)d_in[13];
    const float* Wg1     = (const float*)d_in[14];
    const float* as1     = (const float*)d_in[15];
    const float* ad1     = (const float*)d_in[16];
    const float* bg1     = (const float*)d_in[17];
    const float* Wg2     = (const float*)d_in[18];
    const float* as2     = (const float*)d_in[19];
    const float* ad2     = (const float*)d_in[20];
    const float* bg2     = (const float*)d_in[21];
    const float* Wc1     = (const float*)d_in[22];
    const float* bc1     = (const float*)d_in[23];
    const float* Wc2     = (const float*)d_in[24];
    const float* bc2     = (const float*)d_in[25];
    const float* Wh1     = (const float*)d_in[26];
    const float* bh1     = (const float*)d_in[27];
    const float* Wh2     = (const float*)d_in[28];
    const float* bh2     = (const float*)d_in[29];
    float* out = (float*)d_out;
    float* ws  = (float*)d_ws;

    // workspace carve (floats); h and z ping-pong through the whole net
    float*  gb1         = ws;                       // 128,000
    float*  gb2         = gb1 + 128000;             // 128,000
    half_t* hbuf        = (half_t*)(gb2 + 128000);  // 6.4M halfs
    half_t* zbuf        = hbuf + 6400000;           // 6.4M halfs
    float*  es          = (float*)(zbuf + 6400000); // 100,000
    float*  ed          = es + N_NODES;             // 100,000
    int*    rowptr      = (int*)(ed + N_NODES);     // 100,001
    int*    csr_src     = rowptr + N_NODES + 1;     // 1,200,000
    int*    bucket_cnt  = csr_src + N_EDGES;        // 256 (memset start)
    int*    bucket_fill = bucket_cnt + NBUCK;       // 256 (memset end)
    int*    bucket_base = bucket_fill + NBUCK;      // 257
    int*    staged      = bucket_base + NBUCK + 1;  // 1,200,000

    // CSR build via bucket sort (topology is layer-invariant)
    hipMemsetAsync(bucket_cnt, 0, 2*NBUCK*sizeof(int), stream);
    k_bhist<<<S3_BLOCKS, 1024, 0, stream>>>(ei, bucket_cnt);
    k_bscan<<<1, NBUCK, 0, stream>>>(bucket_cnt, bucket_base);
    k_bin  <<<S3_BLOCKS, 1024, 0, stream>>>(ei, bucket_base, bucket_fill, staged);
    k_bcsr <<<NBUCK, 1024, 0, stream>>>(staged, bucket_base, rowptr, csr_src);

    // prologue (fused LN + FiLM coefficients)
    k_climber_film<<<N_GRAPHS, 128, 0, stream>>>(climber, ln_g, ln_b, W_c, b_c,
                                                 Wf1, bf1, Wf2, bf2, gb1, gb2);

    int nodeBlocks = (N_NODES*16 + 255)/256;   // 6250
    k_node0<<<nodeBlocks, 256, 0, stream>>>(x, batch, W_in, b_in, gb1, hbuf);
    k_mfma_z<<<MFMA_BLOCKS, 256, 0, stream>>>(hbuf, Wg1, as1, ad1, zbuf, es, ed);
    k_agg<<<nodeBlocks, 256, 0, stream>>>(rowptr, csr_src, es, ed, zbuf, bg1,
                                          batch, gb2, 1, hbuf);
    k_mfma_z<<<MFMA_BLOCKS, 256, 0, stream>>>(hbuf, Wg2, as2, ad2, zbuf, es, ed);
    k_agg<<<nodeBlocks, 256, 0, stream>>>(rowptr, csr_src, es, ed, zbuf, bg2,
                                          batch, gb2, 0, hbuf);
    k_head_mfma<<<MFMA_BLOCKS, 256, 0, stream>>>(hbuf, x, Wc1, bc1, Wc2, bc2,
                                                 Wh1, bh1, Wh2, bh2, out);
}

// Round 17
// 272.644 us; speedup vs baseline: 1.4120x; 1.0242x over previous
//
#include <hip/hip_runtime.h>
#include <math.h>

#define N_NODES 100000
#define N_EDGES 1200000
#define N_GRAPHS 1000
#define HID 64
#define NBUCK 256
#define NPB   391
#define BCAP  8192           // fixed staging capacity per bucket (~50 sigma)
#define EDGE_CHUNK 16384
#define S3_BLOCKS ((N_EDGES + EDGE_CHUNK - 1) / EDGE_CHUNK)
#define LOG2E 1.4426950408889634f
#define N_TILES (N_NODES / 16)      // 6250, exact
#define MFMA_BLOCKS 391

typedef _Float16 half_t;
typedef __attribute__((ext_vector_type(4))) _Float16 half4;
typedef __attribute__((ext_vector_type(8))) _Float16 half8;
typedef __attribute__((ext_vector_type(4))) float floatx4;

// ---------------- CSR build: single-pass bin into fixed-capacity buckets -----
// staged entry: (local_dst << 17) | src   (src < 2^17, local_dst < 512)

__global__ void k_bin(const int* __restrict__ ei, int* __restrict__ bucket_fill,
                      int* __restrict__ staged) {
    __shared__ int hist[NBUCK];
    __shared__ int cursor[NBUCK];
    for (int t = threadIdx.x; t < NBUCK; t += blockDim.x) hist[t] = 0;
    __syncthreads();
    int e0 = blockIdx.x * EDGE_CHUNK;
    int e1 = min(e0 + EDGE_CHUNK, N_EDGES);
    for (int e = e0 + threadIdx.x; e < e1; e += blockDim.x)
        atomicAdd(&hist[ei[N_EDGES + e] / NPB], 1);
    __syncthreads();
    if (threadIdx.x < NBUCK) {
        int hv = hist[threadIdx.x];
        int start = threadIdx.x * BCAP;
        if (hv) start += atomicAdd(&bucket_fill[threadIdx.x], hv);
        cursor[threadIdx.x] = start;
    }
    __syncthreads();
    for (int e = e0 + threadIdx.x; e < e1; e += blockDim.x) {
        int src = ei[e], dst = ei[N_EDGES + e];
        int b = dst / NPB;
        int ldst = dst - b * NPB;
        int pos = atomicAdd(&cursor[b], 1);
        staged[pos] = (ldst << 17) | src;
    }
}

// scan final bucket counts -> compact CSR bucket bases
__global__ void k_bscan(const int* __restrict__ bucket_fill, int* __restrict__ bucket_base) {
    __shared__ int sh[NBUCK];
    int t = threadIdx.x;
    int v = bucket_fill[t];
    sh[t] = v;
    __syncthreads();
    for (int off = 1; off < NBUCK; off <<= 1) {
        int u = (t >= off) ? sh[t - off] : 0;
        __syncthreads();
        sh[t] += u;
        __syncthreads();
    }
    bucket_base[t] = sh[t] - v;               // exclusive
    if (t == NBUCK - 1) bucket_base[NBUCK] = sh[t];
}

__global__ void k_bcsr(const int* __restrict__ staged, const int* __restrict__ bucket_base,
                       int* __restrict__ rowptr, int* __restrict__ csr_src) {
    __shared__ int ldeg[NPB];
    __shared__ int sc[512];
    __shared__ int cursor[NPB];
    int b = blockIdx.x;
    int n0 = b * NPB;
    int n1 = min(n0 + NPB, N_NODES);
    int nn = n1 - n0;
    int bbase = bucket_base[b];
    int bcnt  = bucket_base[b+1] - bbase;
    const int* st = staged + b * BCAP;
    for (int t = threadIdx.x; t < NPB; t += blockDim.x) ldeg[t] = 0;
    __syncthreads();
    for (int k = threadIdx.x; k < bcnt; k += blockDim.x)
        atomicAdd(&ldeg[st[k] >> 17], 1);
    __syncthreads();
    if (threadIdx.x < 512) sc[threadIdx.x] = (threadIdx.x < nn) ? ldeg[threadIdx.x] : 0;
    __syncthreads();
    for (int off = 1; off < 512; off <<= 1) {
        int u = 0;
        if (threadIdx.x < 512 && threadIdx.x >= off) u = sc[threadIdx.x - off];
        __syncthreads();
        if (threadIdx.x < 512) sc[threadIdx.x] += u;
        __syncthreads();
    }
    if (threadIdx.x < nn) {
        int pre = sc[threadIdx.x] - ldeg[threadIdx.x];     // exclusive
        rowptr[n0 + threadIdx.x] = bbase + pre;
        cursor[threadIdx.x] = bbase + pre;
    }
    if (b == 0 && threadIdx.x == 0) rowptr[N_NODES] = bucket_base[NBUCK];
    __syncthreads();
    for (int k = threadIdx.x; k < bcnt; k += blockDim.x) {
        int v = st[k];
        int pos = atomicAdd(&cursor[v >> 17], 1);
        csr_src[pos] = v & 0x1FFFF;
    }
}

// ---------------- fused climber LN + FiLM coefficient kernel -----------------
__global__ void k_climber_film(const float* __restrict__ climber,
                               const float* __restrict__ ln_g, const float* __restrict__ ln_b,
                               const float* __restrict__ W_c, const float* __restrict__ b_c,
                               const float* __restrict__ Wf1, const float* __restrict__ bf1,
                               const float* __restrict__ Wf2, const float* __restrict__ bf2,
                               float* __restrict__ gb1, float* __restrict__ gb2) {
    __shared__ float cl[64];
    int g = blockIdx.x;
    int j = threadIdx.x;
    if (j < 64) {
        float v[6];
        float mu = 0.f;
        #pragma unroll
        for (int k = 0; k < 6; k++) { v[k] = climber[g*6+k]; mu += v[k]; }
        mu *= (1.f/6.f);
        float var = 0.f;
        #pragma unroll
        for (int k = 0; k < 6; k++) { float d = v[k]-mu; var += d*d; }
        var *= (1.f/6.f);
        float rs = rsqrtf(var + 1e-5f);
        float acc = b_c[j];
        #pragma unroll
        for (int k = 0; k < 6; k++) {
            float cn = (v[k]-mu)*rs*ln_g[k] + ln_b[k];
            acc += cn * W_c[k*64+j];
        }
        cl[j] = fmaxf(acc, 0.f);
    }
    __syncthreads();
    float a1 = bf1[j], a2 = bf2[j];
    #pragma unroll 8
    for (int k = 0; k < 64; k++) {
        float ck = cl[k];
        a1 += ck * Wf1[k*128+j];
        a2 += ck * Wf2[k*128+j];
    }
    gb1[g*128+j] = a1;
    gb2[g*128+j] = a2;
}

// ---------------- node init: h1 = film1(x@W_in + b_in), fp16 ----------------
__global__ void k_node0(const float* __restrict__ x, const int* __restrict__ batch,
                        const float* __restrict__ W_in, const float* __restrict__ b_in,
                        const float* __restrict__ gb1, half_t* __restrict__ h) {
    int tid = blockIdx.x * blockDim.x + threadIdx.x;
    int i  = tid >> 4;
    int sl = threadIdx.x & 15;
    if (i >= N_NODES) return;
    float4 acc = ((const float4*)b_in)[sl];
    #pragma unroll
    for (int k = 0; k < 6; k++) {
        float xk = x[i*8+k];
        float4 w = ((const float4*)W_in)[k*16 + sl];
        acc.x += xk*w.x; acc.y += xk*w.y; acc.z += xk*w.z; acc.w += xk*w.w;
    }
    int g = batch[i];
    const float4* gb4 = (const float4*)gb1;
    float4 ga = gb4[g*32 + sl];
    float4 be = gb4[g*32 + 16 + sl];
    half4 hv;
    hv.x = (half_t)(acc.x*(1.f+ga.x) + be.x);
    hv.y = (half_t)(acc.y*(1.f+ga.y) + be.y);
    hv.z = (half_t)(acc.z*(1.f+ga.z) + be.z);
    hv.w = (half_t)(acc.w*(1.f+ga.w) + be.w);
    ((half4*)h)[i*16 + sl] = hv;
}

// ---------------- MFMA transform: z = h @ W (fp16 in, fp32 acc) -------------
__global__ __launch_bounds__(256) void k_mfma_z(
        const half_t* __restrict__ h, const float* __restrict__ W,
        const float* __restrict__ a_src, const float* __restrict__ a_dst,
        half_t* __restrict__ z, float* __restrict__ es, float* __restrict__ ed) {
    __shared__ half_t zl[4][16*64];          // per-wave 2 KB transpose staging
    int wave = threadIdx.x >> 6;
    int l    = threadIdx.x & 63;
    int c    = l & 15;
    int g    = l >> 4;
    half8 Bf[2][4];
    #pragma unroll
    for (int ko = 0; ko < 2; ko++) {
        #pragma unroll
        for (int nt = 0; nt < 4; nt++) {
            half8 b;
            #pragma unroll
            for (int j = 0; j < 8; j++)
                b[j] = (half_t)W[(ko*32 + g*8 + j)*64 + c + 16*nt];
            Bf[ko][nt] = b;
        }
    }
    float as4[4], ad4[4];
    #pragma unroll
    for (int nt = 0; nt < 4; nt++) {
        as4[nt] = a_src[c + 16*nt] * LOG2E;
        ad4[nt] = a_dst[c + 16*nt] * LOG2E;
    }
    int nWaves = gridDim.x * 4;
    int wid = blockIdx.x * 4 + wave;
    half_t* zw = zl[wave];
    for (int t = wid; t < N_TILES; t += nWaves) {
        int m0 = t * 16;
        const half8* hrow = (const half8*)(h + (size_t)(m0 + c) * 64);
        half8 A0 = hrow[g];
        half8 A1 = hrow[g + 4];
        floatx4 D[4];
        #pragma unroll
        for (int nt = 0; nt < 4; nt++) {
            floatx4 acc = {0.f, 0.f, 0.f, 0.f};
            acc = __builtin_amdgcn_mfma_f32_16x16x32_f16(A0, Bf[0][nt], acc, 0, 0, 0);
            acc = __builtin_amdgcn_mfma_f32_16x16x32_f16(A1, Bf[1][nt], acc, 0, 0, 0);
            D[nt] = acc;
        }
        #pragma unroll
        for (int r = 0; r < 4; r++) {
            float ps = D[0][r]*as4[0] + D[1][r]*as4[1] + D[2][r]*as4[2] + D[3][r]*as4[3];
            float pd = D[0][r]*ad4[0] + D[1][r]*ad4[1] + D[2][r]*ad4[2] + D[3][r]*ad4[3];
            #pragma unroll
            for (int off = 1; off < 16; off <<= 1) {
                ps += __shfl_xor(ps, off, 16);
                pd += __shfl_xor(pd, off, 16);
            }
            if (c == 0) {
                es[m0 + g*4 + r] = ps;
                ed[m0 + g*4 + r] = pd;
            }
        }
        #pragma unroll
        for (int nt = 0; nt < 4; nt++) {
            #pragma unroll
            for (int r = 0; r < 4; r++)
                zw[(g*4 + r)*64 + c + 16*nt] = (half_t)D[nt][r];
        }
        __asm__ __volatile__("s_waitcnt lgkmcnt(0)" ::: "memory");
        const half8* zr = (const half8*)zw;
        half8 v0 = zr[l*2];
        half8 v1 = zr[l*2 + 1];
        half8* zo = (half8*)(z + (size_t)m0 * 64);
        zo[l*2]     = v0;
        zo[l*2 + 1] = v1;
        __asm__ __volatile__("s_waitcnt lgkmcnt(0)" ::: "memory");
    }
}

// ---------------- gather/softmax aggregation (no transform) ------------------
__device__ __forceinline__ float4 h4_to_f4(half4 h) {
    float4 f;
    f.x = (float)h.x; f.y = (float)h.y; f.z = (float)h.z; f.w = (float)h.w;
    return f;
}

__global__ void k_agg(const int* __restrict__ rowptr, const int* __restrict__ csr_src,
                      const float* __restrict__ es, const float* __restrict__ ed,
                      const half_t* __restrict__ z, const float* __restrict__ bg,
                      const int* __restrict__ batch, const float* __restrict__ gb,
                      int apply_film, half_t* __restrict__ hout) {
    int tid = blockIdx.x * blockDim.x + threadIdx.x;
    int i  = tid >> 4;
    int sl = threadIdx.x & 15;
    if (i >= N_NODES) return;
    int beg = rowptr[i], end = rowptr[i+1];
    int deg = end - beg;
    float edi = ed[i];

    float e_self = es[i] + edi;
    e_self = fmaxf(e_self, 0.2f * e_self);

    int svA = 0, svB = 0;
    float exA = 0.f, exB = 0.f;
    if (sl < deg) {
        svA = csr_src[beg + sl];
        float v = es[svA] + edi;
        exA = exp2f(fmaxf(v, 0.2f * v));
    }
    if (16 + sl < deg) {
        svB = csr_src[beg + 16 + sl];
        float v = es[svB] + edi;
        exB = exp2f(fmaxf(v, 0.2f * v));
    }
    float s = exA + exB;
    #pragma unroll
    for (int off = 1; off < 16; off <<= 1)
        s += __shfl_xor(s, off, 16);
    float ex = exp2f(e_self);
    s += ex;

    const half4* z4 = (const half4*)z;
    float4 zi = h4_to_f4(z4[i*16 + sl]);
    float4 acc = {ex*zi.x, ex*zi.y, ex*zi.z, ex*zi.w};

    int lim = (deg < 32) ? deg : 32;
    int k = 0;
    for (; k + 8 <= lim; k += 8) {
        int a[8]; float e[8];
        if (k < 16) {
            #pragma unroll
            for (int j = 0; j < 8; j++) {
                a[j] = __shfl(svA, k+j, 16);
                e[j] = __shfl(exA, k+j, 16);
            }
        } else {
            #pragma unroll
            for (int j = 0; j < 8; j++) {
                a[j] = __shfl(svB, k-16+j, 16);
                e[j] = __shfl(exB, k-16+j, 16);
            }
        }
        half4 q[8];
        #pragma unroll
        for (int j = 0; j < 8; j++) q[j] = z4[a[j]*16 + sl];
        #pragma unroll
        for (int j = 0; j < 8; j++) {
            float4 r = h4_to_f4(q[j]);
            acc.x += e[j]*r.x; acc.y += e[j]*r.y;
            acc.z += e[j]*r.z; acc.w += e[j]*r.w;
        }
    }
    for (; k + 4 <= lim; k += 4) {
        int a[4]; float e[4];
        if (k < 16) {
            #pragma unroll
            for (int j = 0; j < 4; j++) {
                a[j] = __shfl(svA, k+j, 16);
                e[j] = __shfl(exA, k+j, 16);
            }
        } else {
            #pragma unroll
            for (int j = 0; j < 4; j++) {
                a[j] = __shfl(svB, k-16+j, 16);
                e[j] = __shfl(exB, k-16+j, 16);
            }
        }
        half4 q[4];
        #pragma unroll
        for (int j = 0; j < 4; j++) q[j] = z4[a[j]*16 + sl];
        #pragma unroll
        for (int j = 0; j < 4; j++) {
            float4 r = h4_to_f4(q[j]);
            acc.x += e[j]*r.x; acc.y += e[j]*r.y;
            acc.z += e[j]*r.z; acc.w += e[j]*r.w;
        }
    }
    for (; k < lim; k++) {
        int a; float e2;
        if (k < 16) { a = __shfl(svA, k, 16);    e2 = __shfl(exA, k, 16); }
        else        { a = __shfl(svB, k-16, 16); e2 = __shfl(exB, k-16, 16); }
        float4 zr = h4_to_f4(z4[a*16 + sl]);
        acc.x += e2*zr.x; acc.y += e2*zr.y; acc.z += e2*zr.z; acc.w += e2*zr.w;
    }
    for (int kk = beg + 32; kk < end; kk++) {   // rare: deg > 32
        int sv = csr_src[kk];
        float v = es[sv] + edi;
        float e2 = exp2f(fmaxf(v, 0.2f * v));
        s += e2;
        float4 zr = h4_to_f4(z4[sv*16 + sl]);
        acc.x += e2*zr.x; acc.y += e2*zr.y; acc.z += e2*zr.z; acc.w += e2*zr.w;
    }
    float inv = 1.f / (s + 1e-16f);
    float4 bg4 = ((const float4*)bg)[sl];
    float4 o;
    o.x = fmaxf(acc.x*inv + bg4.x, 0.f);
    o.y = fmaxf(acc.y*inv + bg4.y, 0.f);
    o.z = fmaxf(acc.z*inv + bg4.z, 0.f);
    o.w = fmaxf(acc.w*inv + bg4.w, 0.f);
    if (apply_film) {
        int g = batch[i];
        const float4* gb4 = (const float4*)gb;
        float4 ga = gb4[g*32 + sl];
        float4 be = gb4[g*32 + 16 + sl];
        o.x = o.x*(1.f+ga.x) + be.x;
        o.y = o.y*(1.f+ga.y) + be.y;
        o.z = o.z*(1.f+ga.z) + be.z;
        o.w = o.w*(1.f+ga.w) + be.w;
    }
    half4 hv;
    hv.x = (half_t)o.x; hv.y = (half_t)o.y; hv.z = (half_t)o.z; hv.w = (half_t)o.w;
    ((half4*)hout)[i*16 + sl] = hv;
}

// ---------------- MFMA head: out = relu(h@Wc1+bc1)@Wc2+bc2 + 0.03*flags -----
__global__ __launch_bounds__(256) void k_head_mfma(
        const half_t* __restrict__ h, const float* __restrict__ x,
        const float* __restrict__ Wc1, const float* __restrict__ bc1,
        const float* __restrict__ Wc2, const float* __restrict__ bc2,
        const float* __restrict__ Wh1, const float* __restrict__ bh1,
        const float* __restrict__ Wh2, const float* __restrict__ bh2,
        float* __restrict__ out) {
    int l    = threadIdx.x & 63;
    int c    = l & 15;
    int g    = l >> 4;
    half8 Bf[2][4];
    #pragma unroll
    for (int ko = 0; ko < 2; ko++) {
        #pragma unroll
        for (int nt = 0; nt < 4; nt++) {
            half8 b;
            #pragma unroll
            for (int j = 0; j < 8; j++)
                b[j] = (half_t)Wc1[(ko*32 + g*8 + j)*64 + c + 16*nt];
            Bf[ko][nt] = b;
        }
    }
    float bc1v[4];
    float4 w2[4];
    #pragma unroll
    for (int nt = 0; nt < 4; nt++) {
        bc1v[nt] = bc1[c + 16*nt];
        w2[nt] = ((const float4*)Wc2)[c + 16*nt];
    }
    int nWaves = gridDim.x * 4;
    int wid = blockIdx.x * 4 + (threadIdx.x >> 6);
    for (int t = wid; t < N_TILES; t += nWaves) {
        int m0 = t * 16;
        const half8* hrow = (const half8*)(h + (size_t)(m0 + c) * 64);
        half8 A0 = hrow[g];
        half8 A1 = hrow[g + 4];
        floatx4 D[4];
        #pragma unroll
        for (int nt = 0; nt < 4; nt++) {
            floatx4 acc = {0.f, 0.f, 0.f, 0.f};
            acc = __builtin_amdgcn_mfma_f32_16x16x32_f16(A0, Bf[0][nt], acc, 0, 0, 0);
            acc = __builtin_amdgcn_mfma_f32_16x16x32_f16(A1, Bf[1][nt], acc, 0, 0, 0);
            D[nt] = acc;
        }
        #pragma unroll
        for (int r = 0; r < 4; r++) {
            float4 p = {0.f, 0.f, 0.f, 0.f};
            #pragma unroll
            for (int nt = 0; nt < 4; nt++) {
                float tv = fmaxf(D[nt][r] + bc1v[nt], 0.f);
                p.x += tv * w2[nt].x;
                p.y += tv * w2[nt].y;
                p.z += tv * w2[nt].z;
                p.w += tv * w2[nt].w;
            }
            #pragma unroll
            for (int off = 1; off < 16; off <<= 1) {
                p.x += __shfl_xor(p.x, off, 16);
                p.y += __shfl_xor(p.y, off, 16);
                p.z += __shfl_xor(p.z, off, 16);
                p.w += __shfl_xor(p.w, off, 16);
            }
            if (c == 0) {
                int m = m0 + g*4 + r;
                float f0 = x[m*8+6], f1 = x[m*8+7];
                float t8[8];
                #pragma unroll
                for (int q = 0; q < 8; q++)
                    t8[q] = fmaxf(f0*Wh1[q] + f1*Wh1[8+q] + bh1[q], 0.f);
                float fl[4];
                #pragma unroll
                for (int q = 0; q < 4; q++) {
                    float a = bh2[q];
                    #pragma unroll
                    for (int rr = 0; rr < 8; rr++) a += t8[rr]*Wh2[rr*4+q];
                    fl[q] = a;
                }
                float4 ov;
                ov.x = p.x + bc2[0] + 0.03f*fl[0];
                ov.y = p.y + bc2[1] + 0.03f*fl[1];
                ov.z = p.z + bc2[2] + 0.03f*fl[2];
                ov.w = p.w + bc2[3] + 0.03f*fl[3];
                ((float4*)out)[m] = ov;
            }
        }
    }
}

extern "C" void kernel_launch(void* const* d_in, const int* in_sizes, int n_in,
                              void* d_out, int out_size, void* d_ws, size_t ws_size,
                              hipStream_t stream) {
    const float* x       = (const float*)d_in[0];
    const int*   ei      = (const int*)  d_in[1];
    const int*   batch   = (const int*)  d_in[2];
    const float* climber = (const float*)d_in[3];
    const float* W_in    = (const float*)d_in[4];
    const float* b_in    = (const float*)d_in[5];
    const float* ln_g    = (const float*)d_in[6];
    const float* ln_b    = (const float*)d_in[7];
    const float* W_c     = (const float*)d_in[8];
    const float* b_c     = (const float*)d_in[9];
    const float* Wf1     = (const float*)d_in[10];
    const float* bf1     = (const float*)d_in[11];
    const float* Wf2     = (const float*)d_in[12];
    const float* bf2     = (const float*)d_in[13];
    const float* Wg1     = (const float*)d_in[14];
    const float* as1     = (const float*)d_in[15];
    const float* ad1     = (const float*)d_in[16];
    const float* bg1     = (const float*)d_in[17];
    const float* Wg2     = (const float*)d_in[18];
    const float* as2     = (const float*)d_in[19];
    const float* ad2     = (const float*)d_in[20];
    const float* bg2     = (const float*)d_in[21];
    const float* Wc1     = (const float*)d_in[22];
    const float* bc1     = (const float*)d_in[23];
    const float* Wc2     = (const float*)d_in[24];
    const float* bc2     = (const float*)d_in[25];
    const float* Wh1     = (const float*)d_in[26];
    const float* bh1     = (const float*)d_in[27];
    const float* Wh2     = (const float*)d_in[28];
    const float* bh2     = (const float*)d_in[29];
    float* out = (float*)d_out;
    float* ws  = (float*)d_ws;

    // workspace carve (floats); h and z ping-pong through the whole net
    float*  gb1         = ws;                       // 128,000
    float*  gb2         = gb1 + 128000;             // 128,000
    half_t* hbuf        = (half_t*)(gb2 + 128000);  // 6.4M halfs
    half_t* zbuf        = hbuf + 6400000;           // 6.4M halfs
    float*  es          = (float*)(zbuf + 6400000); // 100,000
    float*  ed          = es + N_NODES;             // 100,000
    int*    rowptr      = (int*)(ed + N_NODES);     // 100,001
    int*    csr_src     = rowptr + N_NODES + 1;     // 1,200,000
    int*    bucket_fill = csr_src + N_EDGES;        // 256 (memset)
    int*    bucket_base = bucket_fill + NBUCK;      // 257
    int*    staged      = bucket_base + NBUCK + 1;  // 256*8192 = 2,097,152

    // CSR build: single edge pass into fixed-capacity buckets, then compact
    hipMemsetAsync(bucket_fill, 0, NBUCK*sizeof(int), stream);
    k_bin  <<<S3_BLOCKS, 1024, 0, stream>>>(ei, bucket_fill, staged);
    k_bscan<<<1, NBUCK, 0, stream>>>(bucket_fill, bucket_base);
    k_bcsr <<<NBUCK, 1024, 0, stream>>>(staged, bucket_base, rowptr, csr_src);

    // prologue (fused LN + FiLM coefficients)
    k_climber_film<<<N_GRAPHS, 128, 0, stream>>>(climber, ln_g, ln_b, W_c, b_c,
                                                 Wf1, bf1, Wf2, bf2, gb1, gb2);

    int nodeBlocks = (N_NODES*16 + 255)/256;   // 6250
    k_node0<<<nodeBlocks, 256, 0, stream>>>(x, batch, W_in, b_in, gb1, hbuf);
    k_mfma_z<<<MFMA_BLOCKS, 256, 0, stream>>>(hbuf, Wg1, as1, ad1, zbuf, es, ed);
    k_agg<<<nodeBlocks, 256, 0, stream>>>(rowptr, csr_src, es, ed, zbuf, bg1,
                                          batch, gb2, 1, hbuf);
    k_mfma_z<<<MFMA_BLOCKS, 256, 0, stream>>>(hbuf, Wg2, as2, ad2, zbuf, es, ed);
    k_agg<<<nodeBlocks, 256, 0, stream>>>(rowptr, csr_src, es, ed, zbuf, bg2,
                                          batch, gb2, 0, hbuf);
    k_head_mfma<<<MFMA_BLOCKS, 256, 0, stream>>>(hbuf, x, Wc1, bc1, Wc2, bc2,
                                                 Wh1, bh1, Wh2, bh2, out);
}

// Round 19
// 265.854 us; speedup vs baseline: 1.4481x; 1.0255x over previous
//
#include <hip/hip_runtime.h>
#include <math.h>

#define N_NODES 100000
#define N_EDGES 1200000
#define N_GRAPHS 1000
#define HID 64
#define NBUCK 256
#define NPB   391
#define BCAP  8192           // fixed staging capacity per bucket (~50 sigma)
#define EDGE_CHUNK 16384
#define S3_BLOCKS ((N_EDGES + EDGE_CHUNK - 1) / EDGE_CHUNK)
#define LOG2E 1.4426950408889634f
#define N_TILES (N_NODES / 16)      // 6250, exact
#define MFMA_BLOCKS 391

typedef _Float16 half_t;
typedef __attribute__((ext_vector_type(4))) _Float16 half4;
typedef __attribute__((ext_vector_type(8))) _Float16 half8;
typedef __attribute__((ext_vector_type(4))) float floatx4;

// ---------------- CSR build: single-pass bin into fixed-capacity buckets -----
// staged entry: (local_dst << 17) | src   (src < 2^17, local_dst < 512)

__global__ void k_bin(const int* __restrict__ ei, int* __restrict__ bucket_fill,
                      int* __restrict__ staged) {
    __shared__ int hist[NBUCK];
    __shared__ int cursor[NBUCK];
    for (int t = threadIdx.x; t < NBUCK; t += blockDim.x) hist[t] = 0;
    __syncthreads();
    int e0 = blockIdx.x * EDGE_CHUNK;
    int e1 = min(e0 + EDGE_CHUNK, N_EDGES);
    for (int e = e0 + threadIdx.x; e < e1; e += blockDim.x)
        atomicAdd(&hist[ei[N_EDGES + e] / NPB], 1);
    __syncthreads();
    if (threadIdx.x < NBUCK) {
        int hv = hist[threadIdx.x];
        int start = threadIdx.x * BCAP;
        if (hv) start += atomicAdd(&bucket_fill[threadIdx.x], hv);
        cursor[threadIdx.x] = start;
    }
    __syncthreads();
    for (int e = e0 + threadIdx.x; e < e1; e += blockDim.x) {
        int src = ei[e], dst = ei[N_EDGES + e];
        int b = dst / NPB;
        int ldst = dst - b * NPB;
        int pos = atomicAdd(&cursor[b], 1);
        staged[pos] = (ldst << 17) | src;
    }
}

// compact staged -> csr_src + rowptr. Each block scans bucket_fill itself.
__global__ void k_bcsr(const int* __restrict__ staged, const int* __restrict__ bucket_fill,
                       int* __restrict__ rowptr, int* __restrict__ csr_src) {
    __shared__ int bb[NBUCK];       // inclusive scan of bucket_fill
    __shared__ int ldeg[NPB];
    __shared__ int sc[512];
    __shared__ int cursor[NPB];
    int b = blockIdx.x;
    if (threadIdx.x < NBUCK) bb[threadIdx.x] = bucket_fill[threadIdx.x];
    __syncthreads();
    for (int off = 1; off < NBUCK; off <<= 1) {
        int u = 0;
        if (threadIdx.x < NBUCK && threadIdx.x >= off) u = bb[threadIdx.x - off];
        __syncthreads();
        if (threadIdx.x < NBUCK) bb[threadIdx.x] += u;
        __syncthreads();
    }
    int bbase = (b == 0) ? 0 : bb[b-1];          // exclusive prefix
    int bcnt  = bb[b] - bbase;
    const int* st = staged + b * BCAP;
    int n0 = b * NPB;
    int n1 = min(n0 + NPB, N_NODES);
    int nn = n1 - n0;
    for (int t = threadIdx.x; t < NPB; t += blockDim.x) ldeg[t] = 0;
    __syncthreads();
    for (int k = threadIdx.x; k < bcnt; k += blockDim.x)
        atomicAdd(&ldeg[st[k] >> 17], 1);
    __syncthreads();
    if (threadIdx.x < 512) sc[threadIdx.x] = (threadIdx.x < nn) ? ldeg[threadIdx.x] : 0;
    __syncthreads();
    for (int off = 1; off < 512; off <<= 1) {
        int u = 0;
        if (threadIdx.x < 512 && threadIdx.x >= off) u = sc[threadIdx.x - off];
        __syncthreads();
        if (threadIdx.x < 512) sc[threadIdx.x] += u;
        __syncthreads();
    }
    if (threadIdx.x < nn) {
        int pre = sc[threadIdx.x] - ldeg[threadIdx.x];     // exclusive
        rowptr[n0 + threadIdx.x] = bbase + pre;
        cursor[threadIdx.x] = bbase + pre;
    }
    if (b == 0 && threadIdx.x == 0) rowptr[N_NODES] = bb[NBUCK-1];
    __syncthreads();
    for (int k = threadIdx.x; k < bcnt; k += blockDim.x) {
        int v = st[k];
        int pos = atomicAdd(&cursor[v >> 17], 1);
        csr_src[pos] = v & 0x1FFFF;
    }
}

// ---------------- fused climber LN + FiLM coefficient kernel -----------------
__global__ void k_climber_film(const float* __restrict__ climber,
                               const float* __restrict__ ln_g, const float* __restrict__ ln_b,
                               const float* __restrict__ W_c, const float* __restrict__ b_c,
                               const float* __restrict__ Wf1, const float* __restrict__ bf1,
                               const float* __restrict__ Wf2, const float* __restrict__ bf2,
                               float* __restrict__ gb1, float* __restrict__ gb2) {
    __shared__ float cl[64];
    int g = blockIdx.x;
    int j = threadIdx.x;
    if (j < 64) {
        float v[6];
        float mu = 0.f;
        #pragma unroll
        for (int k = 0; k < 6; k++) { v[k] = climber[g*6+k]; mu += v[k]; }
        mu *= (1.f/6.f);
        float var = 0.f;
        #pragma unroll
        for (int k = 0; k < 6; k++) { float d = v[k]-mu; var += d*d; }
        var *= (1.f/6.f);
        float rs = rsqrtf(var + 1e-5f);
        float acc = b_c[j];
        #pragma unroll
        for (int k = 0; k < 6; k++) {
            float cn = (v[k]-mu)*rs*ln_g[k] + ln_b[k];
            acc += cn * W_c[k*64+j];
        }
        cl[j] = fmaxf(acc, 0.f);
    }
    __syncthreads();
    float a1 = bf1[j], a2 = bf2[j];
    #pragma unroll 8
    for (int k = 0; k < 64; k++) {
        float ck = cl[k];
        a1 += ck * Wf1[k*128+j];
        a2 += ck * Wf2[k*128+j];
    }
    gb1[g*128+j] = a1;
    gb2[g*128+j] = a2;
}

// ---------------- layer-1 fused MFMA: h1 computed in-register ----------------
// A-fragment lane (c,g) computes its own 16 h-values from x/W_in/FiLM:
// h[i][k] = film1(x[i][0:6] @ W_in[:,k] + b_in[k]),  i = m0+c, k = s*32+g*8+j.
// h1 is never materialized.
__global__ __launch_bounds__(256) void k_mfma_z1(
        const float* __restrict__ x, const int* __restrict__ batch,
        const float* __restrict__ W_in, const float* __restrict__ b_in,
        const float* __restrict__ gb1, const float* __restrict__ W,
        const float* __restrict__ a_src, const float* __restrict__ a_dst,
        half_t* __restrict__ z, float* __restrict__ es, float* __restrict__ ed) {
    __shared__ float Wi[384];                // W_in row-major 6x64
    __shared__ float bi[64];
    __shared__ half_t zl[4][16*64];
    for (int idx = threadIdx.x; idx < 384; idx += 256) Wi[idx] = W_in[idx];
    if (threadIdx.x < 64) bi[threadIdx.x] = b_in[threadIdx.x];
    int wave = threadIdx.x >> 6;
    int l    = threadIdx.x & 63;
    int c    = l & 15;
    int g    = l >> 4;
    half8 Bf[2][4];
    #pragma unroll
    for (int ko = 0; ko < 2; ko++) {
        #pragma unroll
        for (int nt = 0; nt < 4; nt++) {
            half8 bvec;
            #pragma unroll
            for (int j = 0; j < 8; j++)
                bvec[j] = (half_t)W[(ko*32 + g*8 + j)*64 + c + 16*nt];
            Bf[ko][nt] = bvec;
        }
    }
    float as4[4], ad4[4];
    #pragma unroll
    for (int nt = 0; nt < 4; nt++) {
        as4[nt] = a_src[c + 16*nt] * LOG2E;
        ad4[nt] = a_dst[c + 16*nt] * LOG2E;
    }
    __syncthreads();
    int nWaves = gridDim.x * 4;
    int wid = blockIdx.x * 4 + wave;
    half_t* zw = zl[wave];
    for (int t = wid; t < N_TILES; t += nWaves) {
        int m0 = t * 16;
        int i = m0 + c;
        float xv[6];
        #pragma unroll
        for (int kk = 0; kk < 6; kk++) xv[kk] = x[i*8 + kk];
        int bg_ = batch[i];
        half8 A[2];
        #pragma unroll
        for (int s = 0; s < 2; s++) {
            int bk = s*32 + g*8;
            float acc[8];
            #pragma unroll
            for (int j = 0; j < 8; j++) acc[j] = bi[bk + j];
            #pragma unroll
            for (int kk = 0; kk < 6; kk++) {
                float xk = xv[kk];
                float4 w0 = *(const float4*)&Wi[kk*64 + bk];
                float4 w1 = *(const float4*)&Wi[kk*64 + bk + 4];
                acc[0] += xk*w0.x; acc[1] += xk*w0.y;
                acc[2] += xk*w0.z; acc[3] += xk*w0.w;
                acc[4] += xk*w1.x; acc[5] += xk*w1.y;
                acc[6] += xk*w1.z; acc[7] += xk*w1.w;
            }
            const float4* gbv = (const float4*)(gb1 + bg_*128);
            float4 ga0 = gbv[bk/4],      ga1 = gbv[bk/4 + 1];
            float4 be0 = gbv[16 + bk/4], be1 = gbv[16 + bk/4 + 1];
            half8 hv;
            hv[0] = (half_t)(acc[0]*(1.f+ga0.x) + be0.x);
            hv[1] = (half_t)(acc[1]*(1.f+ga0.y) + be0.y);
            hv[2] = (half_t)(acc[2]*(1.f+ga0.z) + be0.z);
            hv[3] = (half_t)(acc[3]*(1.f+ga0.w) + be0.w);
            hv[4] = (half_t)(acc[4]*(1.f+ga1.x) + be1.x);
            hv[5] = (half_t)(acc[5]*(1.f+ga1.y) + be1.y);
            hv[6] = (half_t)(acc[6]*(1.f+ga1.z) + be1.z);
            hv[7] = (half_t)(acc[7]*(1.f+ga1.w) + be1.w);
            A[s] = hv;
        }
        floatx4 D[4];
        #pragma unroll
        for (int nt = 0; nt < 4; nt++) {
            floatx4 acc = {0.f, 0.f, 0.f, 0.f};
            acc = __builtin_amdgcn_mfma_f32_16x16x32_f16(A[0], Bf[0][nt], acc, 0, 0, 0);
            acc = __builtin_amdgcn_mfma_f32_16x16x32_f16(A[1], Bf[1][nt], acc, 0, 0, 0);
            D[nt] = acc;
        }
        #pragma unroll
        for (int r = 0; r < 4; r++) {
            float ps = D[0][r]*as4[0] + D[1][r]*as4[1] + D[2][r]*as4[2] + D[3][r]*as4[3];
            float pd = D[0][r]*ad4[0] + D[1][r]*ad4[1] + D[2][r]*ad4[2] + D[3][r]*ad4[3];
            #pragma unroll
            for (int off = 1; off < 16; off <<= 1) {
                ps += __shfl_xor(ps, off, 16);
                pd += __shfl_xor(pd, off, 16);
            }
            if (c == 0) {
                es[m0 + g*4 + r] = ps;
                ed[m0 + g*4 + r] = pd;
            }
        }
        #pragma unroll
        for (int nt = 0; nt < 4; nt++) {
            #pragma unroll
            for (int r = 0; r < 4; r++)
                zw[(g*4 + r)*64 + c + 16*nt] = (half_t)D[nt][r];
        }
        __asm__ __volatile__("s_waitcnt lgkmcnt(0)" ::: "memory");
        const half8* zr = (const half8*)zw;
        half8 v0 = zr[l*2];
        half8 v1 = zr[l*2 + 1];
        half8* zo = (half8*)(z + (size_t)m0 * 64);
        zo[l*2]     = v0;
        zo[l*2 + 1] = v1;
        __asm__ __volatile__("s_waitcnt lgkmcnt(0)" ::: "memory");
    }
}

// ---------------- MFMA transform: z = h @ W (fp16 in, fp32 acc) -------------
__global__ __launch_bounds__(256) void k_mfma_z(
        const half_t* __restrict__ h, const float* __restrict__ W,
        const float* __restrict__ a_src, const float* __restrict__ a_dst,
        half_t* __restrict__ z, float* __restrict__ es, float* __restrict__ ed) {
    __shared__ half_t zl[4][16*64];
    int wave = threadIdx.x >> 6;
    int l    = threadIdx.x & 63;
    int c    = l & 15;
    int g    = l >> 4;
    half8 Bf[2][4];
    #pragma unroll
    for (int ko = 0; ko < 2; ko++) {
        #pragma unroll
        for (int nt = 0; nt < 4; nt++) {
            half8 b;
            #pragma unroll
            for (int j = 0; j < 8; j++)
                b[j] = (half_t)W[(ko*32 + g*8 + j)*64 + c + 16*nt];
            Bf[ko][nt] = b;
        }
    }
    float as4[4], ad4[4];
    #pragma unroll
    for (int nt = 0; nt < 4; nt++) {
        as4[nt] = a_src[c + 16*nt] * LOG2E;
        ad4[nt] = a_dst[c + 16*nt] * LOG2E;
    }
    int nWaves = gridDim.x * 4;
    int wid = blockIdx.x * 4 + wave;
    half_t* zw = zl[wave];
    for (int t = wid; t < N_TILES; t += nWaves) {
        int m0 = t * 16;
        const half8* hrow = (const half8*)(h + (size_t)(m0 + c) * 64);
        half8 A0 = hrow[g];
        half8 A1 = hrow[g + 4];
        floatx4 D[4];
        #pragma unroll
        for (int nt = 0; nt < 4; nt++) {
            floatx4 acc = {0.f, 0.f, 0.f, 0.f};
            acc = __builtin_amdgcn_mfma_f32_16x16x32_f16(A0, Bf[0][nt], acc, 0, 0, 0);
            acc = __builtin_amdgcn_mfma_f32_16x16x32_f16(A1, Bf[1][nt], acc, 0, 0, 0);
            D[nt] = acc;
        }
        #pragma unroll
        for (int r = 0; r < 4; r++) {
            float ps = D[0][r]*as4[0] + D[1][r]*as4[1] + D[2][r]*as4[2] + D[3][r]*as4[3];
            float pd = D[0][r]*ad4[0] + D[1][r]*ad4[1] + D[2][r]*ad4[2] + D[3][r]*ad4[3];
            #pragma unroll
            for (int off = 1; off < 16; off <<= 1) {
                ps += __shfl_xor(ps, off, 16);
                pd += __shfl_xor(pd, off, 16);
            }
            if (c == 0) {
                es[m0 + g*4 + r] = ps;
                ed[m0 + g*4 + r] = pd;
            }
        }
        #pragma unroll
        for (int nt = 0; nt < 4; nt++) {
            #pragma unroll
            for (int r = 0; r < 4; r++)
                zw[(g*4 + r)*64 + c + 16*nt] = (half_t)D[nt][r];
        }
        __asm__ __volatile__("s_waitcnt lgkmcnt(0)" ::: "memory");
        const half8* zr = (const half8*)zw;
        half8 v0 = zr[l*2];
        half8 v1 = zr[l*2 + 1];
        half8* zo = (half8*)(z + (size_t)m0 * 64);
        zo[l*2]     = v0;
        zo[l*2 + 1] = v1;
        __asm__ __volatile__("s_waitcnt lgkmcnt(0)" ::: "memory");
    }
}

// ---------------- gather/softmax aggregation (no transform) ------------------
__device__ __forceinline__ float4 h4_to_f4(half4 h) {
    float4 f;
    f.x = (float)h.x; f.y = (float)h.y; f.z = (float)h.z; f.w = (float)h.w;
    return f;
}

__global__ void k_agg(const int* __restrict__ rowptr, const int* __restrict__ csr_src,
                      const float* __restrict__ es, const float* __restrict__ ed,
                      const half_t* __restrict__ z, const float* __restrict__ bg,
                      const int* __restrict__ batch, const float* __restrict__ gb,
                      int apply_film, half_t* __restrict__ hout) {
    int tid = blockIdx.x * blockDim.x + threadIdx.x;
    int i  = tid >> 4;
    int sl = threadIdx.x & 15;
    if (i >= N_NODES) return;
    int beg = rowptr[i], end = rowptr[i+1];
    int deg = end - beg;
    float edi = ed[i];

    float e_self = es[i] + edi;
    e_self = fmaxf(e_self, 0.2f * e_self);

    int svA = 0, svB = 0;
    float exA = 0.f, exB = 0.f;
    if (sl < deg) {
        svA = csr_src[beg + sl];
        float v = es[svA] + edi;
        exA = exp2f(fmaxf(v, 0.2f * v));
    }
    if (16 + sl < deg) {
        svB = csr_src[beg + 16 + sl];
        float v = es[svB] + edi;
        exB = exp2f(fmaxf(v, 0.2f * v));
    }
    float s = exA + exB;
    #pragma unroll
    for (int off = 1; off < 16; off <<= 1)
        s += __shfl_xor(s, off, 16);
    float ex = exp2f(e_self);
    s += ex;

    const half4* z4 = (const half4*)z;
    float4 zi = h4_to_f4(z4[i*16 + sl]);
    float4 acc = {ex*zi.x, ex*zi.y, ex*zi.z, ex*zi.w};

    int lim = (deg < 32) ? deg : 32;
    int k = 0;
    for (; k + 8 <= lim; k += 8) {
        int a[8]; float e[8];
        if (k < 16) {
            #pragma unroll
            for (int j = 0; j < 8; j++) {
                a[j] = __shfl(svA, k+j, 16);
                e[j] = __shfl(exA, k+j, 16);
            }
        } else {
            #pragma unroll
            for (int j = 0; j < 8; j++) {
                a[j] = __shfl(svB, k-16+j, 16);
                e[j] = __shfl(exB, k-16+j, 16);
            }
        }
        half4 q[8];
        #pragma unroll
        for (int j = 0; j < 8; j++) q[j] = z4[a[j]*16 + sl];
        #pragma unroll
        for (int j = 0; j < 8; j++) {
            float4 r = h4_to_f4(q[j]);
            acc.x += e[j]*r.x; acc.y += e[j]*r.y;
            acc.z += e[j]*r.z; acc.w += e[j]*r.w;
        }
    }
    for (; k + 4 <= lim; k += 4) {
        int a[4]; float e[4];
        if (k < 16) {
            #pragma unroll
            for (int j = 0; j < 4; j++) {
                a[j] = __shfl(svA, k+j, 16);
                e[j] = __shfl(exA, k+j, 16);
            }
        } else {
            #pragma unroll
            for (int j = 0; j < 4; j++) {
                a[j] = __shfl(svB, k-16+j, 16);
                e[j] = __shfl(exB, k-16+j, 16);
            }
        }
        half4 q[4];
        #pragma unroll
        for (int j = 0; j < 4; j++) q[j] = z4[a[j]*16 + sl];
        #pragma unroll
        for (int j = 0; j < 4; j++) {
            float4 r = h4_to_f4(q[j]);
            acc.x += e[j]*r.x; acc.y += e[j]*r.y;
            acc.z += e[j]*r.z; acc.w += e[j]*r.w;
        }
    }
    for (; k < lim; k++) {
        int a; float e2;
        if (k < 16) { a = __shfl(svA, k, 16);    e2 = __shfl(exA, k, 16); }
        else        { a = __shfl(svB, k-16, 16); e2 = __shfl(exB, k-16, 16); }
        float4 zr = h4_to_f4(z4[a*16 + sl]);
        acc.x += e2*zr.x; acc.y += e2*zr.y; acc.z += e2*zr.z; acc.w += e2*zr.w;
    }
    for (int kk = beg + 32; kk < end; kk++) {   // rare: deg > 32
        int sv = csr_src[kk];
        float v = es[sv] + edi;
        float e2 = exp2f(fmaxf(v, 0.2f * v));
        s += e2;
        float4 zr = h4_to_f4(z4[sv*16 + sl]);
        acc.x += e2*zr.x; acc.y += e2*zr.y; acc.z += e2*zr.z; acc.w += e2*zr.w;
    }
    float inv = 1.f / (s + 1e-16f);
    float4 bg4 = ((const float4*)bg)[sl];
    float4 o;
    o.x = fmaxf(acc.x*inv + bg4.x, 0.f);
    o.y = fmaxf(acc.y*inv + bg4.y, 0.f);
    o.z = fmaxf(acc.z*inv + bg4.z, 0.f);
    o.w = fmaxf(acc.w*inv + bg4.w, 0.f);
    if (apply_film) {
        int g = batch[i];
        const float4* gb4 = (const float4*)gb;
        float4 ga = gb4[g*32 + sl];
        float4 be = gb4[g*32 + 16 + sl];
        o.x = o.x*(1.f+ga.x) + be.x;
        o.y = o.y*(1.f+ga.y) + be.y;
        o.z = o.z*(1.f+ga.z) + be.z;
        o.w = o.w*(1.f+ga.w) + be.w;
    }
    half4 hv;
    hv.x = (half_t)o.x; hv.y = (half_t)o.y; hv.z = (half_t)o.z; hv.w = (half_t)o.w;
    ((half4*)hout)[i*16 + sl] = hv;
}

// ---------------- MFMA head: out = relu(h@Wc1+bc1)@Wc2+bc2 + 0.03*flags -----
__global__ __launch_bounds__(256) void k_head_mfma(
        const half_t* __restrict__ h, const float* __restrict__ x,
        const float* __restrict__ Wc1, const float* __restrict__ bc1,
        const float* __restrict__ Wc2, const float* __restrict__ bc2,
        const float* __restrict__ Wh1, const float* __restrict__ bh1,
        const float* __restrict__ Wh2, const float* __restrict__ bh2,
        float* __restrict__ out) {
    int l    = threadIdx.x & 63;
    int c    = l & 15;
    int g    = l >> 4;
    half8 Bf[2][4];
    #pragma unroll
    for (int ko = 0; ko < 2; ko++) {
        #pragma unroll
        for (int nt = 0; nt < 4; nt++) {
            half8 b;
            #pragma unroll
            for (int j = 0; j < 8; j++)
                b[j] = (half_t)Wc1[(ko*32 + g*8 + j)*64 + c + 16*nt];
            Bf[ko][nt] = b;
        }
    }
    float bc1v[4];
    float4 w2[4];
    #pragma unroll
    for (int nt = 0; nt < 4; nt++) {
        bc1v[nt] = bc1[c + 16*nt];
        w2[nt] = ((const float4*)Wc2)[c + 16*nt];
    }
    int nWaves = gridDim.x * 4;
    int wid = blockIdx.x * 4 + (threadIdx.x >> 6);
    for (int t = wid; t < N_TILES; t += nWaves) {
        int m0 = t * 16;
        const half8* hrow = (const half8*)(h + (size_t)(m0 + c) * 64);
        half8 A0 = hrow[g];
        half8 A1 = hrow[g + 4];
        floatx4 D[4];
        #pragma unroll
        for (int nt = 0; nt < 4; nt++) {
            floatx4 acc = {0.f, 0.f, 0.f, 0.f};
            acc = __builtin_amdgcn_mfma_f32_16x16x32_f16(A0, Bf[0][nt], acc, 0, 0, 0);
            acc = __builtin_amdgcn_mfma_f32_16x16x32_f16(A1, Bf[1][nt], acc, 0, 0, 0);
            D[nt] = acc;
        }
        #pragma unroll
        for (int r = 0; r < 4; r++) {
            float4 p = {0.f, 0.f, 0.f, 0.f};
            #pragma unroll
            for (int nt = 0; nt < 4; nt++) {
                float tv = fmaxf(D[nt][r] + bc1v[nt], 0.f);
                p.x += tv * w2[nt].x;
                p.y += tv * w2[nt].y;
                p.z += tv * w2[nt].z;
                p.w += tv * w2[nt].w;
            }
            #pragma unroll
            for (int off = 1; off < 16; off <<= 1) {
                p.x += __shfl_xor(p.x, off, 16);
                p.y += __shfl_xor(p.y, off, 16);
                p.z += __shfl_xor(p.z, off, 16);
                p.w += __shfl_xor(p.w, off, 16);
            }
            if (c == 0) {
                int m = m0 + g*4 + r;
                float f0 = x[m*8+6], f1 = x[m*8+7];
                float t8[8];
                #pragma unroll
                for (int q = 0; q < 8; q++)
                    t8[q] = fmaxf(f0*Wh1[q] + f1*Wh1[8+q] + bh1[q], 0.f);
                float fl[4];
                #pragma unroll
                for (int q = 0; q < 4; q++) {
                    float a = bh2[q];
                    #pragma unroll
                    for (int rr = 0; rr < 8; rr++) a += t8[rr]*Wh2[rr*4+q];
                    fl[q] = a;
                }
                float4 ov;
                ov.x = p.x + bc2[0] + 0.03f*fl[0];
                ov.y = p.y + bc2[1] + 0.03f*fl[1];
                ov.z = p.z + bc2[2] + 0.03f*fl[2];
                ov.w = p.w + bc2[3] + 0.03f*fl[3];
                ((float4*)out)[m] = ov;
            }
        }
    }
}

extern "C" void kernel_launch(void* const* d_in, const int* in_sizes, int n_in,
                              void* d_out, int out_size, void* d_ws, size_t ws_size,
                              hipStream_t stream) {
    const float* x       = (const float*)d_in[0];
    const int*   ei      = (const int*)  d_in[1];
    const int*   batch   = (const int*)  d_in[2];
    const float* climber = (const float*)d_in[3];
    const float* W_in    = (const float*)d_in[4];
    const float* b_in    = (const float*)d_in[5];
    const float* ln_g    = (const float*)d_in[6];
    const float* ln_b    = (const float*)d_in[7];
    const float* W_c     = (const float*)d_in[8];
    const float* b_c     = (const float*)d_in[9];
    const float* Wf1     = (const float*)d_in[10];
    const float* bf1     = (const float*)d_in[11];
    const float* Wf2     = (const float*)d_in[12];
    const float* bf2     = (const float*)d_in[13];
    const float* Wg1     = (const float*)d_in[14];
    const float* as1     = (const float*)d_in[15];
    const float* ad1     = (const float*)d_in[16];
    const float* bg1     = (const float*)d_in[17];
    const float* Wg2     = (const float*)d_in[18];
    const float* as2     = (const float*)d_in[19];
    const float* ad2     = (const float*)d_in[20];
    const float* bg2     = (const float*)d_in[21];
    const float* Wc1     = (const float*)d_in[22];
    const float* bc1     = (const float*)d_in[23];
    const float* Wc2     = (const float*)d_in[24];
    const float* bc2     = (const float*)d_in[25];
    const float* Wh1     = (const float*)d_in[26];
    const float* bh1     = (const float*)d_in[27];
    const float* Wh2     = (const float*)d_in[28];
    const float* bh2     = (const float*)d_in[29];
    float* out = (float*)d_out;
    float* ws  = (float*)d_ws;

    // workspace carve (floats)
    float*  gb1         = ws;                       // 128,000
    float*  gb2         = gb1 + 128000;             // 128,000
    half_t* hbuf        = (half_t*)(gb2 + 128000);  // 6.4M halfs
    half_t* zbuf        = hbuf + 6400000;           // 6.4M halfs
    float*  es          = (float*)(zbuf + 6400000); // 100,000
    float*  ed          = es + N_NODES;             // 100,000
    int*    rowptr      = (int*)(ed + N_NODES);     // 100,001
    int*    csr_src     = rowptr + N_NODES + 1;     // 1,200,000
    int*    bucket_fill = csr_src + N_EDGES;        // 256 (memset)
    int*    staged      = bucket_fill + NBUCK;      // 256*8192 = 2,097,152

    // CSR build: single edge pass into fixed-capacity buckets, then compact
    hipMemsetAsync(bucket_fill, 0, NBUCK*sizeof(int), stream);
    k_bin <<<S3_BLOCKS, 1024, 0, stream>>>(ei, bucket_fill, staged);
    k_bcsr<<<NBUCK, 1024, 0, stream>>>(staged, bucket_fill, rowptr, csr_src);

    // prologue (fused LN + FiLM coefficients)
    k_climber_film<<<N_GRAPHS, 128, 0, stream>>>(climber, ln_g, ln_b, W_c, b_c,
                                                 Wf1, bf1, Wf2, bf2, gb1, gb2);

    int nodeBlocks = (N_NODES*16 + 255)/256;   // 6250
    k_mfma_z1<<<MFMA_BLOCKS, 256, 0, stream>>>(x, batch, W_in, b_in, gb1, Wg1,
                                               as1, ad1, zbuf, es, ed);
    k_agg<<<nodeBlocks, 256, 0, stream>>>(rowptr, csr_src, es, ed, zbuf, bg1,
                                          batch, gb2, 1, hbuf);
    k_mfma_z<<<MFMA_BLOCKS, 256, 0, stream>>>(hbuf, Wg2, as2, ad2, zbuf, es, ed);
    k_agg<<<nodeBlocks, 256, 0, stream>>>(rowptr, csr_src, es, ed, zbuf, bg2,
                                          batch, gb2, 0, hbuf);
    k_head_mfma<<<MFMA_BLOCKS, 256, 0, stream>>>(hbuf, x, Wc1, bc1, Wc2, bc2,
                                                 Wh1, bh1, Wh2, bh2, out);
}

// Round 20
// 259.915 us; speedup vs baseline: 1.4812x; 1.0228x over previous
//
#include <hip/hip_runtime.h>
#include <math.h>

#define N_NODES 100000
#define N_EDGES 1200000
#define N_GRAPHS 1000
#define HID 64
#define NBUCK 256
#define NPB   391
#define BCAP  8192           // fixed staging capacity per bucket (~50 sigma)
#define EDGE_CHUNK 16384
#define S3_BLOCKS ((N_EDGES + EDGE_CHUNK - 1) / EDGE_CHUNK)
#define LOG2E 1.4426950408889634f
#define N_TILES (N_NODES / 16)      // 6250, exact
#define MFMA_BLOCKS 391

typedef _Float16 half_t;
typedef __attribute__((ext_vector_type(4))) _Float16 half4;
typedef __attribute__((ext_vector_type(8))) _Float16 half8;
typedef __attribute__((ext_vector_type(4))) float floatx4;

// ---------------- fused climber LN + FiLM coefficients + bucket_fill zero ----
// Block 0 additionally zeroes bucket_fill (stream order => done before k_bin).
__global__ void k_climber_film(const float* __restrict__ climber,
                               const float* __restrict__ ln_g, const float* __restrict__ ln_b,
                               const float* __restrict__ W_c, const float* __restrict__ b_c,
                               const float* __restrict__ Wf1, const float* __restrict__ bf1,
                               const float* __restrict__ Wf2, const float* __restrict__ bf2,
                               float* __restrict__ gb1, float* __restrict__ gb2,
                               int* __restrict__ bucket_fill) {
    __shared__ float cl[64];
    int g = blockIdx.x;
    int j = threadIdx.x;
    if (g == 0) {
        bucket_fill[j] = 0;
        bucket_fill[j + 128] = 0;
    }
    if (j < 64) {
        float v[6];
        float mu = 0.f;
        #pragma unroll
        for (int k = 0; k < 6; k++) { v[k] = climber[g*6+k]; mu += v[k]; }
        mu *= (1.f/6.f);
        float var = 0.f;
        #pragma unroll
        for (int k = 0; k < 6; k++) { float d = v[k]-mu; var += d*d; }
        var *= (1.f/6.f);
        float rs = rsqrtf(var + 1e-5f);
        float acc = b_c[j];
        #pragma unroll
        for (int k = 0; k < 6; k++) {
            float cn = (v[k]-mu)*rs*ln_g[k] + ln_b[k];
            acc += cn * W_c[k*64+j];
        }
        cl[j] = fmaxf(acc, 0.f);
    }
    __syncthreads();
    float a1 = bf1[j], a2 = bf2[j];
    #pragma unroll 8
    for (int k = 0; k < 64; k++) {
        float ck = cl[k];
        a1 += ck * Wf1[k*128+j];
        a2 += ck * Wf2[k*128+j];
    }
    gb1[g*128+j] = a1;
    gb2[g*128+j] = a2;
}

// ---------------- CSR build: single-pass bin into fixed-capacity buckets -----
// staged entry: (local_dst << 17) | src   (src < 2^17, local_dst < 512)

__global__ void k_bin(const int* __restrict__ ei, int* __restrict__ bucket_fill,
                      int* __restrict__ staged) {
    __shared__ int hist[NBUCK];
    __shared__ int cursor[NBUCK];
    for (int t = threadIdx.x; t < NBUCK; t += blockDim.x) hist[t] = 0;
    __syncthreads();
    int e0 = blockIdx.x * EDGE_CHUNK;
    int e1 = min(e0 + EDGE_CHUNK, N_EDGES);
    for (int e = e0 + threadIdx.x; e < e1; e += blockDim.x)
        atomicAdd(&hist[ei[N_EDGES + e] / NPB], 1);
    __syncthreads();
    if (threadIdx.x < NBUCK) {
        int hv = hist[threadIdx.x];
        int start = threadIdx.x * BCAP;
        if (hv) start += atomicAdd(&bucket_fill[threadIdx.x], hv);
        cursor[threadIdx.x] = start;
    }
    __syncthreads();
    for (int e = e0 + threadIdx.x; e < e1; e += blockDim.x) {
        int src = ei[e], dst = ei[N_EDGES + e];
        int b = dst / NPB;
        int ldst = dst - b * NPB;
        int pos = atomicAdd(&cursor[b], 1);
        staged[pos] = (ldst << 17) | src;
    }
}

// compact staged -> csr_src + rowptr. Each block scans bucket_fill itself.
__global__ void k_bcsr(const int* __restrict__ staged, const int* __restrict__ bucket_fill,
                       int* __restrict__ rowptr, int* __restrict__ csr_src) {
    __shared__ int bb[NBUCK];       // inclusive scan of bucket_fill
    __shared__ int ldeg[NPB];
    __shared__ int sc[512];
    __shared__ int cursor[NPB];
    int b = blockIdx.x;
    if (threadIdx.x < NBUCK) bb[threadIdx.x] = bucket_fill[threadIdx.x];
    __syncthreads();
    for (int off = 1; off < NBUCK; off <<= 1) {
        int u = 0;
        if (threadIdx.x < NBUCK && threadIdx.x >= off) u = bb[threadIdx.x - off];
        __syncthreads();
        if (threadIdx.x < NBUCK) bb[threadIdx.x] += u;
        __syncthreads();
    }
    int bbase = (b == 0) ? 0 : bb[b-1];          // exclusive prefix
    int bcnt  = bb[b] - bbase;
    const int* st = staged + b * BCAP;
    int n0 = b * NPB;
    int n1 = min(n0 + NPB, N_NODES);
    int nn = n1 - n0;
    for (int t = threadIdx.x; t < NPB; t += blockDim.x) ldeg[t] = 0;
    __syncthreads();
    for (int k = threadIdx.x; k < bcnt; k += blockDim.x)
        atomicAdd(&ldeg[st[k] >> 17], 1);
    __syncthreads();
    if (threadIdx.x < 512) sc[threadIdx.x] = (threadIdx.x < nn) ? ldeg[threadIdx.x] : 0;
    __syncthreads();
    for (int off = 1; off < 512; off <<= 1) {
        int u = 0;
        if (threadIdx.x < 512 && threadIdx.x >= off) u = sc[threadIdx.x - off];
        __syncthreads();
        if (threadIdx.x < 512) sc[threadIdx.x] += u;
        __syncthreads();
    }
    if (threadIdx.x < nn) {
        int pre = sc[threadIdx.x] - ldeg[threadIdx.x];     // exclusive
        rowptr[n0 + threadIdx.x] = bbase + pre;
        cursor[threadIdx.x] = bbase + pre;
    }
    if (b == 0 && threadIdx.x == 0) rowptr[N_NODES] = bb[NBUCK-1];
    __syncthreads();
    for (int k = threadIdx.x; k < bcnt; k += blockDim.x) {
        int v = st[k];
        int pos = atomicAdd(&cursor[v >> 17], 1);
        csr_src[pos] = v & 0x1FFFF;
    }
}

// ---------------- layer-1 fused MFMA: h1 computed in-register ----------------
__global__ __launch_bounds__(256) void k_mfma_z1(
        const float* __restrict__ x, const int* __restrict__ batch,
        const float* __restrict__ W_in, const float* __restrict__ b_in,
        const float* __restrict__ gb1, const float* __restrict__ W,
        const float* __restrict__ a_src, const float* __restrict__ a_dst,
        half_t* __restrict__ z, float* __restrict__ es, float* __restrict__ ed) {
    __shared__ float Wi[384];                // W_in row-major 6x64
    __shared__ float bi[64];
    __shared__ half_t zl[4][16*64];
    for (int idx = threadIdx.x; idx < 384; idx += 256) Wi[idx] = W_in[idx];
    if (threadIdx.x < 64) bi[threadIdx.x] = b_in[threadIdx.x];
    int wave = threadIdx.x >> 6;
    int l    = threadIdx.x & 63;
    int c    = l & 15;
    int g    = l >> 4;
    half8 Bf[2][4];
    #pragma unroll
    for (int ko = 0; ko < 2; ko++) {
        #pragma unroll
        for (int nt = 0; nt < 4; nt++) {
            half8 bvec;
            #pragma unroll
            for (int j = 0; j < 8; j++)
                bvec[j] = (half_t)W[(ko*32 + g*8 + j)*64 + c + 16*nt];
            Bf[ko][nt] = bvec;
        }
    }
    float as4[4], ad4[4];
    #pragma unroll
    for (int nt = 0; nt < 4; nt++) {
        as4[nt] = a_src[c + 16*nt] * LOG2E;
        ad4[nt] = a_dst[c + 16*nt] * LOG2E;
    }
    __syncthreads();
    int nWaves = gridDim.x * 4;
    int wid = blockIdx.x * 4 + wave;
    half_t* zw = zl[wave];
    for (int t = wid; t < N_TILES; t += nWaves) {
        int m0 = t * 16;
        int i = m0 + c;
        float xv[6];
        #pragma unroll
        for (int kk = 0; kk < 6; kk++) xv[kk] = x[i*8 + kk];
        int bg_ = batch[i];
        half8 A[2];
        #pragma unroll
        for (int s = 0; s < 2; s++) {
            int bk = s*32 + g*8;
            float acc[8];
            #pragma unroll
            for (int j = 0; j < 8; j++) acc[j] = bi[bk + j];
            #pragma unroll
            for (int kk = 0; kk < 6; kk++) {
                float xk = xv[kk];
                float4 w0 = *(const float4*)&Wi[kk*64 + bk];
                float4 w1 = *(const float4*)&Wi[kk*64 + bk + 4];
                acc[0] += xk*w0.x; acc[1] += xk*w0.y;
                acc[2] += xk*w0.z; acc[3] += xk*w0.w;
                acc[4] += xk*w1.x; acc[5] += xk*w1.y;
                acc[6] += xk*w1.z; acc[7] += xk*w1.w;
            }
            const float4* gbv = (const float4*)(gb1 + bg_*128);
            float4 ga0 = gbv[bk/4],      ga1 = gbv[bk/4 + 1];
            float4 be0 = gbv[16 + bk/4], be1 = gbv[16 + bk/4 + 1];
            half8 hv;
            hv[0] = (half_t)(acc[0]*(1.f+ga0.x) + be0.x);
            hv[1] = (half_t)(acc[1]*(1.f+ga0.y) + be0.y);
            hv[2] = (half_t)(acc[2]*(1.f+ga0.z) + be0.z);
            hv[3] = (half_t)(acc[3]*(1.f+ga0.w) + be0.w);
            hv[4] = (half_t)(acc[4]*(1.f+ga1.x) + be1.x);
            hv[5] = (half_t)(acc[5]*(1.f+ga1.y) + be1.y);
            hv[6] = (half_t)(acc[6]*(1.f+ga1.z) + be1.z);
            hv[7] = (half_t)(acc[7]*(1.f+ga1.w) + be1.w);
            A[s] = hv;
        }
        floatx4 D[4];
        #pragma unroll
        for (int nt = 0; nt < 4; nt++) {
            floatx4 acc = {0.f, 0.f, 0.f, 0.f};
            acc = __builtin_amdgcn_mfma_f32_16x16x32_f16(A[0], Bf[0][nt], acc, 0, 0, 0);
            acc = __builtin_amdgcn_mfma_f32_16x16x32_f16(A[1], Bf[1][nt], acc, 0, 0, 0);
            D[nt] = acc;
        }
        #pragma unroll
        for (int r = 0; r < 4; r++) {
            float ps = D[0][r]*as4[0] + D[1][r]*as4[1] + D[2][r]*as4[2] + D[3][r]*as4[3];
            float pd = D[0][r]*ad4[0] + D[1][r]*ad4[1] + D[2][r]*ad4[2] + D[3][r]*ad4[3];
            #pragma unroll
            for (int off = 1; off < 16; off <<= 1) {
                ps += __shfl_xor(ps, off, 16);
                pd += __shfl_xor(pd, off, 16);
            }
            if (c == 0) {
                es[m0 + g*4 + r] = ps;
                ed[m0 + g*4 + r] = pd;
            }
        }
        #pragma unroll
        for (int nt = 0; nt < 4; nt++) {
            #pragma unroll
            for (int r = 0; r < 4; r++)
                zw[(g*4 + r)*64 + c + 16*nt] = (half_t)D[nt][r];
        }
        __asm__ __volatile__("s_waitcnt lgkmcnt(0)" ::: "memory");
        const half8* zr = (const half8*)zw;
        half8 v0 = zr[l*2];
        half8 v1 = zr[l*2 + 1];
        half8* zo = (half8*)(z + (size_t)m0 * 64);
        zo[l*2]     = v0;
        zo[l*2 + 1] = v1;
        __asm__ __volatile__("s_waitcnt lgkmcnt(0)" ::: "memory");
    }
}

// ---------------- MFMA transform: z = h @ W (fp16 in, fp32 acc) -------------
__global__ __launch_bounds__(256) void k_mfma_z(
        const half_t* __restrict__ h, const float* __restrict__ W,
        const float* __restrict__ a_src, const float* __restrict__ a_dst,
        half_t* __restrict__ z, float* __restrict__ es, float* __restrict__ ed) {
    __shared__ half_t zl[4][16*64];
    int wave = threadIdx.x >> 6;
    int l    = threadIdx.x & 63;
    int c    = l & 15;
    int g    = l >> 4;
    half8 Bf[2][4];
    #pragma unroll
    for (int ko = 0; ko < 2; ko++) {
        #pragma unroll
        for (int nt = 0; nt < 4; nt++) {
            half8 b;
            #pragma unroll
            for (int j = 0; j < 8; j++)
                b[j] = (half_t)W[(ko*32 + g*8 + j)*64 + c + 16*nt];
            Bf[ko][nt] = b;
        }
    }
    float as4[4], ad4[4];
    #pragma unroll
    for (int nt = 0; nt < 4; nt++) {
        as4[nt] = a_src[c + 16*nt] * LOG2E;
        ad4[nt] = a_dst[c + 16*nt] * LOG2E;
    }
    int nWaves = gridDim.x * 4;
    int wid = blockIdx.x * 4 + wave;
    half_t* zw = zl[wave];
    for (int t = wid; t < N_TILES; t += nWaves) {
        int m0 = t * 16;
        const half8* hrow = (const half8*)(h + (size_t)(m0 + c) * 64);
        half8 A0 = hrow[g];
        half8 A1 = hrow[g + 4];
        floatx4 D[4];
        #pragma unroll
        for (int nt = 0; nt < 4; nt++) {
            floatx4 acc = {0.f, 0.f, 0.f, 0.f};
            acc = __builtin_amdgcn_mfma_f32_16x16x32_f16(A0, Bf[0][nt], acc, 0, 0, 0);
            acc = __builtin_amdgcn_mfma_f32_16x16x32_f16(A1, Bf[1][nt], acc, 0, 0, 0);
            D[nt] = acc;
        }
        #pragma unroll
        for (int r = 0; r < 4; r++) {
            float ps = D[0][r]*as4[0] + D[1][r]*as4[1] + D[2][r]*as4[2] + D[3][r]*as4[3];
            float pd = D[0][r]*ad4[0] + D[1][r]*ad4[1] + D[2][r]*ad4[2] + D[3][r]*ad4[3];
            #pragma unroll
            for (int off = 1; off < 16; off <<= 1) {
                ps += __shfl_xor(ps, off, 16);
                pd += __shfl_xor(pd, off, 16);
            }
            if (c == 0) {
                es[m0 + g*4 + r] = ps;
                ed[m0 + g*4 + r] = pd;
            }
        }
        #pragma unroll
        for (int nt = 0; nt < 4; nt++) {
            #pragma unroll
            for (int r = 0; r < 4; r++)
                zw[(g*4 + r)*64 + c + 16*nt] = (half_t)D[nt][r];
        }
        __asm__ __volatile__("s_waitcnt lgkmcnt(0)" ::: "memory");
        const half8* zr = (const half8*)zw;
        half8 v0 = zr[l*2];
        half8 v1 = zr[l*2 + 1];
        half8* zo = (half8*)(z + (size_t)m0 * 64);
        zo[l*2]     = v0;
        zo[l*2 + 1] = v1;
        __asm__ __volatile__("s_waitcnt lgkmcnt(0)" ::: "memory");
    }
}

// ---------------- gather/softmax aggregation (no transform) ------------------
__device__ __forceinline__ float4 h4_to_f4(half4 h) {
    float4 f;
    f.x = (float)h.x; f.y = (float)h.y; f.z = (float)h.z; f.w = (float)h.w;
    return f;
}

__global__ void k_agg(const int* __restrict__ rowptr, const int* __restrict__ csr_src,
                      const float* __restrict__ es, const float* __restrict__ ed,
                      const half_t* __restrict__ z, const float* __restrict__ bg,
                      const int* __restrict__ batch, const float* __restrict__ gb,
                      int apply_film, half_t* __restrict__ hout) {
    int tid = blockIdx.x * blockDim.x + threadIdx.x;
    int i  = tid >> 4;
    int sl = threadIdx.x & 15;
    if (i >= N_NODES) return;
    int beg = rowptr[i], end = rowptr[i+1];
    int deg = end - beg;
    float edi = ed[i];

    float e_self = es[i] + edi;
    e_self = fmaxf(e_self, 0.2f * e_self);

    int svA = 0, svB = 0;
    float exA = 0.f, exB = 0.f;
    if (sl < deg) {
        svA = csr_src[beg + sl];
        float v = es[svA] + edi;
        exA = exp2f(fmaxf(v, 0.2f * v));
    }
    if (16 + sl < deg) {
        svB = csr_src[beg + 16 + sl];
        float v = es[svB] + edi;
        exB = exp2f(fmaxf(v, 0.2f * v));
    }
    float s = exA + exB;
    #pragma unroll
    for (int off = 1; off < 16; off <<= 1)
        s += __shfl_xor(s, off, 16);
    float ex = exp2f(e_self);
    s += ex;

    const half4* z4 = (const half4*)z;
    float4 zi = h4_to_f4(z4[i*16 + sl]);
    float4 acc = {ex*zi.x, ex*zi.y, ex*zi.z, ex*zi.w};

    int lim = (deg < 32) ? deg : 32;
    int k = 0;
    for (; k + 8 <= lim; k += 8) {
        int a[8]; float e[8];
        if (k < 16) {
            #pragma unroll
            for (int j = 0; j < 8; j++) {
                a[j] = __shfl(svA, k+j, 16);
                e[j] = __shfl(exA, k+j, 16);
            }
        } else {
            #pragma unroll
            for (int j = 0; j < 8; j++) {
                a[j] = __shfl(svB, k-16+j, 16);
                e[j] = __shfl(exB, k-16+j, 16);
            }
        }
        half4 q[8];
        #pragma unroll
        for (int j = 0; j < 8; j++) q[j] = z4[a[j]*16 + sl];
        #pragma unroll
        for (int j = 0; j < 8; j++) {
            float4 r = h4_to_f4(q[j]);
            acc.x += e[j]*r.x; acc.y += e[j]*r.y;
            acc.z += e[j]*r.z; acc.w += e[j]*r.w;
        }
    }
    for (; k + 4 <= lim; k += 4) {
        int a[4]; float e[4];
        if (k < 16) {
            #pragma unroll
            for (int j = 0; j < 4; j++) {
                a[j] = __shfl(svA, k+j, 16);
                e[j] = __shfl(exA, k+j, 16);
            }
        } else {
            #pragma unroll
            for (int j = 0; j < 4; j++) {
                a[j] = __shfl(svB, k-16+j, 16);
                e[j] = __shfl(exB, k-16+j, 16);
            }
        }
        half4 q[4];
        #pragma unroll
        for (int j = 0; j < 4; j++) q[j] = z4[a[j]*16 + sl];
        #pragma unroll
        for (int j = 0; j < 4; j++) {
            float4 r = h4_to_f4(q[j]);
            acc.x += e[j]*r.x; acc.y += e[j]*r.y;
            acc.z += e[j]*r.z; acc.w += e[j]*r.w;
        }
    }
    for (; k < lim; k++) {
        int a; float e2;
        if (k < 16) { a = __shfl(svA, k, 16);    e2 = __shfl(exA, k, 16); }
        else        { a = __shfl(svB, k-16, 16); e2 = __shfl(exB, k-16, 16); }
        float4 zr = h4_to_f4(z4[a*16 + sl]);
        acc.x += e2*zr.x; acc.y += e2*zr.y; acc.z += e2*zr.z; acc.w += e2*zr.w;
    }
    for (int kk = beg + 32; kk < end; kk++) {   // rare: deg > 32
        int sv = csr_src[kk];
        float v = es[sv] + edi;
        float e2 = exp2f(fmaxf(v, 0.2f * v));
        s += e2;
        float4 zr = h4_to_f4(z4[sv*16 + sl]);
        acc.x += e2*zr.x; acc.y += e2*zr.y; acc.z += e2*zr.z; acc.w += e2*zr.w;
    }
    float inv = 1.f / (s + 1e-16f);
    float4 bg4 = ((const float4*)bg)[sl];
    float4 o;
    o.x = fmaxf(acc.x*inv + bg4.x, 0.f);
    o.y = fmaxf(acc.y*inv + bg4.y, 0.f);
    o.z = fmaxf(acc.z*inv + bg4.z, 0.f);
    o.w = fmaxf(acc.w*inv + bg4.w, 0.f);
    if (apply_film) {
        int g = batch[i];
        const float4* gb4 = (const float4*)gb;
        float4 ga = gb4[g*32 + sl];
        float4 be = gb4[g*32 + 16 + sl];
        o.x = o.x*(1.f+ga.x) + be.x;
        o.y = o.y*(1.f+ga.y) + be.y;
        o.z = o.z*(1.f+ga.z) + be.z;
        o.w = o.w*(1.f+ga.w) + be.w;
    }
    half4 hv;
    hv.x = (half_t)o.x; hv.y = (half_t)o.y; hv.z = (half_t)o.z; hv.w = (half_t)o.w;
    ((half4*)hout)[i*16 + sl] = hv;
}

// ---------------- MFMA head: out = relu(h@Wc1+bc1)@Wc2+bc2 + 0.03*flags -----
__global__ __launch_bounds__(256) void k_head_mfma(
        const half_t* __restrict__ h, const float* __restrict__ x,
        const float* __restrict__ Wc1, const float* __restrict__ bc1,
        const float* __restrict__ Wc2, const float* __restrict__ bc2,
        const float* __restrict__ Wh1, const float* __restrict__ bh1,
        const float* __restrict__ Wh2, const float* __restrict__ bh2,
        float* __restrict__ out) {
    int l    = threadIdx.x & 63;
    int c    = l & 15;
    int g    = l >> 4;
    half8 Bf[2][4];
    #pragma unroll
    for (int ko = 0; ko < 2; ko++) {
        #pragma unroll
        for (int nt = 0; nt < 4; nt++) {
            half8 b;
            #pragma unroll
            for (int j = 0; j < 8; j++)
                b[j] = (half_t)Wc1[(ko*32 + g*8 + j)*64 + c + 16*nt];
            Bf[ko][nt] = b;
        }
    }
    float bc1v[4];
    float4 w2[4];
    #pragma unroll
    for (int nt = 0; nt < 4; nt++) {
        bc1v[nt] = bc1[c + 16*nt];
        w2[nt] = ((const float4*)Wc2)[c + 16*nt];
    }
    int nWaves = gridDim.x * 4;
    int wid = blockIdx.x * 4 + (threadIdx.x >> 6);
    for (int t = wid; t < N_TILES; t += nWaves) {
        int m0 = t * 16;
        const half8* hrow = (const half8*)(h + (size_t)(m0 + c) * 64);
        half8 A0 = hrow[g];
        half8 A1 = hrow[g + 4];
        floatx4 D[4];
        #pragma unroll
        for (int nt = 0; nt < 4; nt++) {
            floatx4 acc = {0.f, 0.f, 0.f, 0.f};
            acc = __builtin_amdgcn_mfma_f32_16x16x32_f16(A0, Bf[0][nt], acc, 0, 0, 0);
            acc = __builtin_amdgcn_mfma_f32_16x16x32_f16(A1, Bf[1][nt], acc, 0, 0, 0);
            D[nt] = acc;
        }
        #pragma unroll
        for (int r = 0; r < 4; r++) {
            float4 p = {0.f, 0.f, 0.f, 0.f};
            #pragma unroll
            for (int nt = 0; nt < 4; nt++) {
                float tv = fmaxf(D[nt][r] + bc1v[nt], 0.f);
                p.x += tv * w2[nt].x;
                p.y += tv * w2[nt].y;
                p.z += tv * w2[nt].z;
                p.w += tv * w2[nt].w;
            }
            #pragma unroll
            for (int off = 1; off < 16; off <<= 1) {
                p.x += __shfl_xor(p.x, off, 16);
                p.y += __shfl_xor(p.y, off, 16);
                p.z += __shfl_xor(p.z, off, 16);
                p.w += __shfl_xor(p.w, off, 16);
            }
            if (c == 0) {
                int m = m0 + g*4 + r;
                float f0 = x[m*8+6], f1 = x[m*8+7];
                float t8[8];
                #pragma unroll
                for (int q = 0; q < 8; q++)
                    t8[q] = fmaxf(f0*Wh1[q] + f1*Wh1[8+q] + bh1[q], 0.f);
                float fl[4];
                #pragma unroll
                for (int q = 0; q < 4; q++) {
                    float a = bh2[q];
                    #pragma unroll
                    for (int rr = 0; rr < 8; rr++) a += t8[rr]*Wh2[rr*4+q];
                    fl[q] = a;
                }
                float4 ov;
                ov.x = p.x + bc2[0] + 0.03f*fl[0];
                ov.y = p.y + bc2[1] + 0.03f*fl[1];
                ov.z = p.z + bc2[2] + 0.03f*fl[2];
                ov.w = p.w + bc2[3] + 0.03f*fl[3];
                ((float4*)out)[m] = ov;
            }
        }
    }
}

extern "C" void kernel_launch(void* const* d_in, const int* in_sizes, int n_in,
                              void* d_out, int out_size, void* d_ws, size_t ws_size,
                              hipStream_t stream) {
    const float* x       = (const float*)d_in[0];
    const int*   ei      = (const int*)  d_in[1];
    const int*   batch   = (const int*)  d_in[2];
    const float* climber = (const float*)d_in[3];
    const float* W_in    = (const float*)d_in[4];
    const float* b_in    = (const float*)d_in[5];
    const float* ln_g    = (const float*)d_in[6];
    const float* ln_b    = (const float*)d_in[7];
    const float* W_c     = (const float*)d_in[8];
    const float* b_c     = (const float*)d_in[9];
    const float* Wf1     = (const float*)d_in[10];
    const float* bf1     = (const float*)d_in[11];
    const float* Wf2     = (const float*)d_in[12];
    const float* bf2     = (const float*)d_in[13];
    const float* Wg1     = (const float*)d_in[14];
    const float* as1     = (const float*)d_in[15];
    const float* ad1     = (const float*)d_in[16];
    const float* bg1     = (const float*)d_in[17];
    const float* Wg2     = (const float*)d_in[18];
    const float* as2     = (const float*)d_in[19];
    const float* ad2     = (const float*)d_in[20];
    const float* bg2     = (const float*)d_in[21];
    const float* Wc1     = (const float*)d_in[22];
    const float* bc1     = (const float*)d_in[23];
    const float* Wc2     = (const float*)d_in[24];
    const float* bc2     = (const float*)d_in[25];
    const float* Wh1     = (const float*)d_in[26];
    const float* bh1     = (const float*)d_in[27];
    const float* Wh2     = (const float*)d_in[28];
    const float* bh2     = (const float*)d_in[29];
    float* out = (float*)d_out;
    float* ws  = (float*)d_ws;

    // workspace carve (floats)
    float*  gb1         = ws;                       // 128,000
    float*  gb2         = gb1 + 128000;             // 128,000
    half_t* hbuf        = (half_t*)(gb2 + 128000);  // 6.4M halfs
    half_t* zbuf        = hbuf + 6400000;           // 6.4M halfs
    float*  es          = (float*)(zbuf + 6400000); // 100,000
    float*  ed          = es + N_NODES;             // 100,000
    int*    rowptr      = (int*)(ed + N_NODES);     // 100,001
    int*    csr_src     = rowptr + N_NODES + 1;     // 1,200,000
    int*    bucket_fill = csr_src + N_EDGES;        // 256 (zeroed by k_climber_film)
    int*    staged      = bucket_fill + NBUCK;      // 256*8192 = 2,097,152

    // prologue first: zeroes bucket_fill (block 0) + FiLM coefficients
    k_climber_film<<<N_GRAPHS, 128, 0, stream>>>(climber, ln_g, ln_b, W_c, b_c,
                                                 Wf1, bf1, Wf2, bf2, gb1, gb2,
                                                 bucket_fill);

    // CSR build: single edge pass into fixed-capacity buckets, then compact
    k_bin <<<S3_BLOCKS, 1024, 0, stream>>>(ei, bucket_fill, staged);
    k_bcsr<<<NBUCK, 1024, 0, stream>>>(staged, bucket_fill, rowptr, csr_src);

    int nodeBlocks = (N_NODES*16 + 255)/256;   // 6250
    k_mfma_z1<<<MFMA_BLOCKS, 256, 0, stream>>>(x, batch, W_in, b_in, gb1, Wg1,
                                               as1, ad1, zbuf, es, ed);
    k_agg<<<nodeBlocks, 256, 0, stream>>>(rowptr, csr_src, es, ed, zbuf, bg1,
                                          batch, gb2, 1, hbuf);
    k_mfma_z<<<MFMA_BLOCKS, 256, 0, stream>>>(hbuf, Wg2, as2, ad2, zbuf, es, ed);
    k_agg<<<nodeBlocks, 256, 0, stream>>>(rowptr, csr_src, es, ed, zbuf, bg2,
                                          batch, gb2, 0, hbuf);
    k_head_mfma<<<MFMA_BLOCKS, 256, 0, stream>>>(hbuf, x, Wc1, bc1, Wc2, bc2,
                                                 Wh1, bh1, Wh2, bh2, out);
}